// Round 14
// baseline (477.445 us; speedup 1.0000x reference)
//
#include <hip/hip_runtime.h>
#include <math.h>

#define NN 100000
#define NE 1600000
#define NG 256
#define NPART 200
#define PS 500                        // nodes per partition (9 bits)
#define CAP 9000                      // bucket capacity (mean 8000, +11 sigma)
#define EPB 2048                      // edges per bucket_k block
#define NBLK ((NE + EPB - 1) / EPB)   // 782
#define DEGB 64                       // degree bins for counting sort
static constexpr float BN_EPS = 1e-5f;

// ---- fp16 helpers (HW RNE via v_cvt) ----
__device__ inline float h2f(unsigned short u) {
    _Float16 h; __builtin_memcpy(&h, &u, 2); return (float)h;
}
__device__ inline unsigned short f2h(float f) {
    _Float16 h = (_Float16)f; unsigned short u; __builtin_memcpy(&u, &h, 2); return u;
}
__device__ inline unsigned int pack2(float a, float b) {
    return (unsigned int)f2h(a) | ((unsigned int)f2h(b) << 16);
}

// ======= CSR stage 1: bucket edges by dst partition; packed u32 payload ======
__global__ __launch_bounds__(256) void bucket_k(const int* __restrict__ src,
                                                const int* __restrict__ dst,
                                                int* __restrict__ bcur,
                                                unsigned int* __restrict__ bpk) {
    __shared__ int cnt[NPART];
    __shared__ int base[NPART];
    int t = threadIdx.x;
    for (int i = t; i < NPART; i += 256) cnt[i] = 0;
    __syncthreads();
    int eb = blockIdx.x * EPB + t * 8;   // all-or-nothing (tail is 64x8)
    bool act = eb < NE;
    int myp[8], myr[8];
    unsigned int pk[8];
    if (act) {
        int4 d0 = *reinterpret_cast<const int4*>(dst + eb);
        int4 d1 = *reinterpret_cast<const int4*>(dst + eb + 4);
        int4 s0 = *reinterpret_cast<const int4*>(src + eb);
        int4 s1 = *reinterpret_cast<const int4*>(src + eb + 4);
        int dd[8] = {d0.x,d0.y,d0.z,d0.w,d1.x,d1.y,d1.z,d1.w};
        int ss[8] = {s0.x,s0.y,s0.z,s0.w,s1.x,s1.y,s1.z,s1.w};
        #pragma unroll
        for (int i = 0; i < 8; i++) {
            int p = dd[i] / PS;
            myp[i] = p;
            pk[i] = ((unsigned int)ss[i] << 9) | (unsigned int)(dd[i] - p * PS);
            myr[i] = atomicAdd(&cnt[p], 1);
        }
    }
    __syncthreads();
    for (int i = t; i < NPART; i += 256)
        base[i] = cnt[i] ? atomicAdd(&bcur[i], cnt[i]) : 0;
    __syncthreads();
    if (act) {
        #pragma unroll
        for (int i = 0; i < 8; i++)
            bpk[myp[i] * CAP + base[myp[i]] + myr[i]] = pk[i];
    }
}

// ==== CSR stage 2: hist + scan + LPT-striped deg-sort perm + place ===========
__global__ __launch_bounds__(256) void build_k(const int* __restrict__ bcur,
                                               const unsigned int* __restrict__ bpk,
                                               int* __restrict__ rowptr,
                                               int* __restrict__ csr,
                                               int* __restrict__ perm) {
    __shared__ int hist[PS];          // histogram -> cursor
    __shared__ int allc[NPART];
    __shared__ int psum[256];
    __shared__ int bc[DEGB];
    int p = blockIdx.x, t = threadIdx.x;
    int lo = p * PS;
    if (t < NPART) allc[t] = bcur[t];
    for (int i = t; i < PS; i += 256) hist[i] = 0;
    if (t < DEGB) bc[t] = 0;
    __syncthreads();
    int base = 0;
    for (int q = 0; q < p; q++) base += allc[q];
    int cnt = allc[p];
    const unsigned int* bp = bpk + p * CAP;
    const uint4* bp4 = reinterpret_cast<const uint4*>(bp);
    int n4 = cnt >> 2;
    for (int i = t; i < n4; i += 256) {
        uint4 v = bp4[i];
        atomicAdd(&hist[v.x & 511u], 1);
        atomicAdd(&hist[v.y & 511u], 1);
        atomicAdd(&hist[v.z & 511u], 1);
        atomicAdd(&hist[v.w & 511u], 1);
    }
    for (int i = 4 * n4 + t; i < cnt; i += 256) atomicAdd(&hist[bp[i] & 511u], 1);
    __syncthreads();
    int j0 = t * 2;
    int d0v = 0, d1v = 0, tsum = 0;
    if (j0 < PS) {
        d0v = hist[j0]; d1v = hist[j0 + 1];
        tsum = d0v + d1v;
        atomicAdd(&bc[d0v < DEGB ? d0v : DEGB - 1], 1);
        atomicAdd(&bc[d1v < DEGB ? d1v : DEGB - 1], 1);
    }
    psum[t] = tsum;
    __syncthreads();
    for (int off = 1; off < 256; off <<= 1) {
        int v = (t >= off) ? psum[t - off] : 0;
        __syncthreads();
        psum[t] += v;
        __syncthreads();
    }
    int texcl = psum[t] - tsum;
    if (j0 < PS) {
        int run = base + texcl;
        hist[j0] = run; rowptr[lo + j0] = run; run += d0v;
        hist[j0 + 1] = run; rowptr[lo + j0 + 1] = run; run += d1v;
    }
    if (p == NPART - 1 && t == 0) rowptr[NN] = base + cnt;
    __syncthreads();
    if (t == 0) {
        int run = 0;
        #pragma unroll
        for (int b = 0; b < DEGB; b++) { int c = bc[b]; bc[b] = run; run += c; }
    }
    __syncthreads();
    // LPT-striped perm: rank r (ascending degree) -> global slot (PS-1-r)*NPART+p
    // => gid-order is DESCENDING degree, blocks of 64 gid span one rank stripe.
    if (j0 < PS) {
        int r0 = atomicAdd(&bc[d0v < DEGB ? d0v : DEGB - 1], 1);
        perm[(PS - 1 - r0) * NPART + p] = lo + j0;
        int r1 = atomicAdd(&bc[d1v < DEGB ? d1v : DEGB - 1], 1);
        perm[(PS - 1 - r1) * NPART + p] = lo + j0 + 1;
    }
    __syncthreads();
    for (int i = t; i < n4; i += 256) {
        uint4 v = bp4[i];
        csr[atomicAdd(&hist[v.x & 511u], 1)] = v.x >> 9;
        csr[atomicAdd(&hist[v.y & 511u], 1)] = v.y >> 9;
        csr[atomicAdd(&hist[v.z & 511u], 1)] = v.z >> 9;
        csr[atomicAdd(&hist[v.w & 511u], 1)] = v.w >> 9;
    }
    for (int i = 4 * n4 + t; i < cnt; i += 256)
        csr[atomicAdd(&hist[bp[i] & 511u], 1)] = bp[i] >> 9;
}

// ====== layer 1: 128 threads = 64 nodes x 2 lanes, shfl-combined gather ======
__global__ __launch_bounds__(128) void gmlp1_k(
        const float* __restrict__ x, const int* __restrict__ perm,
        const int* __restrict__ rowptr, const int* __restrict__ csr,
        const float* __restrict__ w_in, const float* __restrict__ b_in,
        const float* __restrict__ w_out, const float* __restrict__ b_out,
        unsigned short* __restrict__ zout, float* __restrict__ stats) {
    __shared__ float lwi[64], lbi[32], lwo[1024], lbo[32];
    __shared__ float zin[64][33];
    int t = threadIdx.x;
    int n = t >> 1, q = t & 1, c0 = q * 16;
    for (int i = t; i < 1024; i += 128) lwo[i] = w_out[i];
    if (t < 64) lwi[t] = w_in[t];
    if (t < 32) { lbi[t] = b_in[t]; lbo[t] = b_out[t]; }
    __syncthreads();
    int gid = blockIdx.x * 64 + n;
    bool act = gid < NN;
    int node = act ? perm[gid] : 0;
    float h0 = 0.f, h1 = 0.f;
    if (act) {
        int rs = rowptr[node], re = rowptr[node + 1];
        if (q == 0) {
            float2 self = *reinterpret_cast<const float2*>(x + 2 * (size_t)node);
            h0 = self.x; h1 = self.y;
        }
        float g0 = 0.f, g1 = 0.f;
        int k = rs + q;           // lane q takes every other neighbor
        for (; k + 6 < re; k += 8) {
            int s0 = csr[k], s1 = csr[k + 2], s2 = csr[k + 4], s3 = csr[k + 6];
            float2 v0 = *reinterpret_cast<const float2*>(x + 2 * (size_t)s0);
            float2 v1 = *reinterpret_cast<const float2*>(x + 2 * (size_t)s1);
            float2 v2 = *reinterpret_cast<const float2*>(x + 2 * (size_t)s2);
            float2 v3 = *reinterpret_cast<const float2*>(x + 2 * (size_t)s3);
            h0 += v0.x + v2.x; h1 += v0.y + v2.y;
            g0 += v1.x + v3.x; g1 += v1.y + v3.y;
        }
        for (; k < re; k += 2) {
            int s = csr[k];
            float2 v = *reinterpret_cast<const float2*>(x + 2 * (size_t)s);
            h0 += v.x; h1 += v.y;
        }
        h0 += g0; h1 += g1;
    }
    h0 += __shfl_xor(h0, 1);
    h1 += __shfl_xor(h1, 1);
    float y[16];
    #pragma unroll
    for (int j = 0; j < 16; j++) {
        float a = lbi[c0 + j] + h0 * lwi[c0 + j] + h1 * lwi[32 + c0 + j];
        y[j] = a > 0.f ? a : 0.f;
    }
    #pragma unroll
    for (int j = 0; j < 16; j++) zin[n][c0 + j] = act ? y[j] : 0.f;
    __syncthreads();
    float o[16];
    #pragma unroll
    for (int j = 0; j < 16; j++) o[j] = lbo[c0 + j];
    #pragma unroll
    for (int c = 0; c < 32; c++) {
        float yv = zin[n][c];
        #pragma unroll
        for (int j = 0; j < 16; j++) o[j] += yv * lwo[c * 32 + c0 + j];
    }
    #pragma unroll
    for (int j = 0; j < 16; j++) o[j] = o[j] > 0.f ? o[j] : 0.f;
    if (act) {
        unsigned short* zo = zout + (size_t)node * 32 + c0;
        uint4 wa, wb;
        wa.x = pack2(o[0], o[1]);   wa.y = pack2(o[2], o[3]);
        wa.z = pack2(o[4], o[5]);   wa.w = pack2(o[6], o[7]);
        wb.x = pack2(o[8], o[9]);   wb.y = pack2(o[10], o[11]);
        wb.z = pack2(o[12], o[13]); wb.w = pack2(o[14], o[15]);
        *reinterpret_cast<uint4*>(zo) = wa;
        *reinterpret_cast<uint4*>(zo + 8) = wb;
    }
    __syncthreads();
    #pragma unroll
    for (int j = 0; j < 16; j++) zin[n][c0 + j] = act ? o[j] : 0.f;
    __syncthreads();
    if (t < 32) {
        float s = 0.f, sq = 0.f;
        for (int nn = 0; nn < 64; nn++) {
            float v = zin[nn][t];
            s += v; sq += v * v;
        }
        atomicAdd(&stats[t], s);
        atomicAdd(&stats[32 + t], sq);
    }
}

// ==== heavy layer: 128 threads = 64 nodes x 2 lanes, 4-row-unrolled gather ===
__global__ __launch_bounds__(128) void gmlp32_k(
        const unsigned short* __restrict__ z, const int* __restrict__ perm,
        const float* __restrict__ statsIn,
        const float* __restrict__ gamma, const float* __restrict__ beta,
        const int* __restrict__ rowptr, const int* __restrict__ csr,
        const float* __restrict__ w_in, const float* __restrict__ b_in,
        const float* __restrict__ w_out, const float* __restrict__ b_out,
        unsigned short* __restrict__ zout, float* __restrict__ statsOut) {
    __shared__ float lwi[1024], lwo[1024], lbi[32], lbo[32], lsc[64];
    __shared__ float zin[64][33];
    int t = threadIdx.x;
    int n = t >> 1, q = t & 1, c0 = q * 16;
    for (int i = t; i < 1024; i += 128) { lwi[i] = w_in[i]; lwo[i] = w_out[i]; }
    if (t < 32) {
        lbi[t] = b_in[t]; lbo[t] = b_out[t];
        float mean = statsIn[t] * (1.f / NN);
        float var  = statsIn[32 + t] * (1.f / NN) - mean * mean;
        float scale = gamma[t] * rsqrtf(var + BN_EPS);
        lsc[t] = scale;
        lsc[32 + t] = beta[t] - mean * scale;
    }
    __syncthreads();
    int gid = blockIdx.x * 64 + n;
    bool act = gid < NN;
    int node = act ? perm[gid] : 0;
    float a[16];
    #pragma unroll
    for (int j = 0; j < 16; j++) a[j] = 0.f;
    float cntf = 0.f;
    if (act) {
        int rs = rowptr[node], re = rowptr[node + 1];
        cntf = (float)(re - rs + 1);
        const unsigned short* zb = z + (size_t)node * 32 + c0;
        uint4 sa = *reinterpret_cast<const uint4*>(zb);
        uint4 sb = *reinterpret_cast<const uint4*>(zb + 8);
        const unsigned short* pa = reinterpret_cast<const unsigned short*>(&sa);
        const unsigned short* pb = reinterpret_cast<const unsigned short*>(&sb);
        #pragma unroll
        for (int j = 0; j < 8; j++) { a[j] = h2f(pa[j]); a[8 + j] = h2f(pb[j]); }
        int k = rs;
        for (; k + 4 <= re; k += 4) {
            int s0 = csr[k], s1 = csr[k + 1], s2 = csr[k + 2], s3 = csr[k + 3];
            const unsigned short* r0 = z + (size_t)s0 * 32 + c0;
            const unsigned short* r1 = z + (size_t)s1 * 32 + c0;
            const unsigned short* r2 = z + (size_t)s2 * 32 + c0;
            const unsigned short* r3 = z + (size_t)s3 * 32 + c0;
            uint4 v0a = *reinterpret_cast<const uint4*>(r0);
            uint4 v0b = *reinterpret_cast<const uint4*>(r0 + 8);
            uint4 v1a = *reinterpret_cast<const uint4*>(r1);
            uint4 v1b = *reinterpret_cast<const uint4*>(r1 + 8);
            uint4 v2a = *reinterpret_cast<const uint4*>(r2);
            uint4 v2b = *reinterpret_cast<const uint4*>(r2 + 8);
            uint4 v3a = *reinterpret_cast<const uint4*>(r3);
            uint4 v3b = *reinterpret_cast<const uint4*>(r3 + 8);
            const unsigned short* q0a = reinterpret_cast<const unsigned short*>(&v0a);
            const unsigned short* q0b = reinterpret_cast<const unsigned short*>(&v0b);
            const unsigned short* q1a = reinterpret_cast<const unsigned short*>(&v1a);
            const unsigned short* q1b = reinterpret_cast<const unsigned short*>(&v1b);
            const unsigned short* q2a = reinterpret_cast<const unsigned short*>(&v2a);
            const unsigned short* q2b = reinterpret_cast<const unsigned short*>(&v2b);
            const unsigned short* q3a = reinterpret_cast<const unsigned short*>(&v3a);
            const unsigned short* q3b = reinterpret_cast<const unsigned short*>(&v3b);
            #pragma unroll
            for (int j = 0; j < 8; j++) {
                a[j]     += (h2f(q0a[j]) + h2f(q1a[j])) + (h2f(q2a[j]) + h2f(q3a[j]));
                a[8 + j] += (h2f(q0b[j]) + h2f(q1b[j])) + (h2f(q2b[j]) + h2f(q3b[j]));
            }
        }
        for (; k < re; k++) {
            int s = csr[k];
            const unsigned short* r = z + (size_t)s * 32 + c0;
            uint4 va = *reinterpret_cast<const uint4*>(r);
            uint4 vb = *reinterpret_cast<const uint4*>(r + 8);
            const unsigned short* qa = reinterpret_cast<const unsigned short*>(&va);
            const unsigned short* qb = reinterpret_cast<const unsigned short*>(&vb);
            #pragma unroll
            for (int j = 0; j < 8; j++) { a[j] += h2f(qa[j]); a[8 + j] += h2f(qb[j]); }
        }
    }
    #pragma unroll
    for (int j = 0; j < 16; j++)
        zin[n][c0 + j] = act ? (a[j] * lsc[c0 + j] + cntf * lsc[32 + c0 + j]) : 0.f;
    __syncthreads();
    float y[16];
    #pragma unroll
    for (int j = 0; j < 16; j++) y[j] = lbi[c0 + j];
    #pragma unroll
    for (int c = 0; c < 32; c++) {
        float zv = zin[n][c];
        #pragma unroll
        for (int j = 0; j < 16; j++) y[j] += zv * lwi[c * 32 + c0 + j];
    }
    #pragma unroll
    for (int j = 0; j < 16; j++) y[j] = y[j] > 0.f ? y[j] : 0.f;
    __syncthreads();
    #pragma unroll
    for (int j = 0; j < 16; j++) zin[n][c0 + j] = y[j];
    __syncthreads();
    float o[16];
    #pragma unroll
    for (int j = 0; j < 16; j++) o[j] = lbo[c0 + j];
    #pragma unroll
    for (int c = 0; c < 32; c++) {
        float yv = zin[n][c];
        #pragma unroll
        for (int j = 0; j < 16; j++) o[j] += yv * lwo[c * 32 + c0 + j];
    }
    #pragma unroll
    for (int j = 0; j < 16; j++) o[j] = o[j] > 0.f ? o[j] : 0.f;
    if (act) {
        unsigned short* zo = zout + (size_t)node * 32 + c0;
        uint4 wa, wb;
        wa.x = pack2(o[0], o[1]);   wa.y = pack2(o[2], o[3]);
        wa.z = pack2(o[4], o[5]);   wa.w = pack2(o[6], o[7]);
        wb.x = pack2(o[8], o[9]);   wb.y = pack2(o[10], o[11]);
        wb.z = pack2(o[12], o[13]); wb.w = pack2(o[14], o[15]);
        *reinterpret_cast<uint4*>(zo) = wa;
        *reinterpret_cast<uint4*>(zo + 8) = wb;
    }
    __syncthreads();
    #pragma unroll
    for (int j = 0; j < 16; j++) zin[n][c0 + j] = act ? o[j] : 0.f;
    __syncthreads();
    if (t < 32) {
        float s = 0.f, sq = 0.f;
        for (int nn = 0; nn < 64; nn++) {
            float v = zin[nn][t];
            s += v; sq += v * v;
        }
        atomicAdd(&statsOut[t], s);
        atomicAdd(&statsOut[32 + t], sq);
    }
}

// ====== pool: batch is SORTED -> one block per graph, binary search ======
__global__ __launch_bounds__(256) void pool_seg_k(
        const unsigned short* __restrict__ z,
        const float* __restrict__ statsIn,
        const float* __restrict__ gamma, const float* __restrict__ beta,
        const int* __restrict__ batch, float* __restrict__ g) {
    __shared__ float lsc[64];
    __shared__ float part[32][33];
    int t = threadIdx.x, slot = t >> 3, q = t & 7, c0 = q * 4;
    int gr = blockIdx.x;
    if (t < 32) {
        float mean = statsIn[t] * (1.f / NN);
        float var  = statsIn[32 + t] * (1.f / NN) - mean * mean;
        float scale = gamma[t] * rsqrtf(var + BN_EPS);
        lsc[t] = scale;
        lsc[32 + t] = beta[t] - mean * scale;
    }
    int lo = 0, hi = NN;
    while (lo < hi) { int mid = (lo + hi) >> 1; if (batch[mid] < gr) lo = mid + 1; else hi = mid; }
    int start = lo;
    hi = NN;
    while (lo < hi) { int mid = (lo + hi) >> 1; if (batch[mid] < gr + 1) lo = mid + 1; else hi = mid; }
    int end = lo;
    float a0 = 0.f, a1 = 0.f, a2 = 0.f, a3 = 0.f;
    for (int i = start + slot; i < end; i += 32) {
        ushort4 v = *reinterpret_cast<const ushort4*>(z + (size_t)i * 32 + c0);
        a0 += h2f(v.x); a1 += h2f(v.y); a2 += h2f(v.z); a3 += h2f(v.w);
    }
    part[slot][c0+0] = a0; part[slot][c0+1] = a1;
    part[slot][c0+2] = a2; part[slot][c0+3] = a3;
    __syncthreads();
    if (t < 32) {
        float s = 0.f;
        for (int sl = 0; sl < 32; sl++) s += part[sl][t];
        float cnt = (float)(end - start);
        g[(size_t)gr * 32 + t] = s * lsc[t] + cnt * lsc[32 + t];
    }
}

// ---------------- head: fc1 -> relu -> fc2 -> log_softmax ----------------
__global__ __launch_bounds__(256) void head_k(
        const float* __restrict__ g,
        const float* __restrict__ fc1w, const float* __restrict__ fc1b,
        const float* __restrict__ fc2w, const float* __restrict__ fc2b,
        float* __restrict__ out) {
    __shared__ float lw1[1024], lb1[32], lw2[64], lb2[2];
    int t = threadIdx.x;
    for (int i = t; i < 1024; i += 256) lw1[i] = fc1w[i];
    if (t < 32) lb1[t] = fc1b[t];
    if (t < 64) lw2[t] = fc2w[t];
    if (t < 2) lb2[t] = fc2b[t];
    __syncthreads();
    float gv[32];
    #pragma unroll
    for (int c = 0; c < 32; c++) gv[c] = g[(size_t)t * 32 + c];
    float o0 = lb2[0], o1 = lb2[1];
    #pragma unroll 4
    for (int k = 0; k < 32; k++) {
        float a = lb1[k];
        #pragma unroll
        for (int c = 0; c < 32; c++) a += gv[c] * lw1[c * 32 + k];
        a = a > 0.f ? a : 0.f;
        o0 += a * lw2[k * 2 + 0];
        o1 += a * lw2[k * 2 + 1];
    }
    float m = fmaxf(o0, o1);
    float lse = m + logf(expf(o0 - m) + expf(o1 - m));
    out[t * 2 + 0] = o0 - lse;
    out[t * 2 + 1] = o1 - lse;
}

extern "C" void kernel_launch(void* const* d_in, const int* in_sizes, int n_in,
                              void* d_out, int out_size, void* d_ws, size_t ws_size,
                              hipStream_t stream) {
    const float* x      = (const float*)d_in[0];
    const int*   ei     = (const int*)d_in[1];
    const int*   src    = ei;
    const int*   dst    = ei + NE;
    const int*   batch  = (const int*)d_in[2];
    const float* w1_in  = (const float*)d_in[3];
    const float* b1_in  = (const float*)d_in[4];
    const float* w1_out = (const float*)d_in[5];
    const float* b1_out = (const float*)d_in[6];
    const float* ws_in  = (const float*)d_in[7];
    const float* bs_in  = (const float*)d_in[8];
    const float* ws_out = (const float*)d_in[9];
    const float* bs_out = (const float*)d_in[10];
    const float* gamma  = (const float*)d_in[11];
    const float* beta   = (const float*)d_in[12];
    const float* fc1w   = (const float*)d_in[13];
    const float* fc1b   = (const float*)d_in[14];
    const float* fc2w   = (const float*)d_in[15];
    const float* fc2b   = (const float*)d_in[16];
    float* out = (float*)d_out;

    // ---- workspace layout (16B alignment maintained) ----
    unsigned short* bufA = (unsigned short*)d_ws;        // NN*32 fp16
    unsigned short* bufB = bufA + (size_t)NN * 32;       // NN*32 fp16
    float* stats  = (float*)(bufB + (size_t)NN * 32);    // 5*64 (zeroed)
    int*   bcur   = (int*)(stats + 5 * 64);              // NPART (zeroed, adjacent)
    float* g      = (float*)(bcur + NPART);              // NG*32
    int*   perm   = (int*)(g + (size_t)NG * 32);         // NN
    int*   rowptr = perm + NN;                           // NN+4
    int*   csr    = rowptr + NN + 4;                     // NE
    unsigned int* bpk = (unsigned int*)(csr + NE);       // NPART*CAP

    // ---- zero stats + bucket cursors in one memset ----
    hipMemsetAsync(stats, 0, (size_t)(5 * 64 + NPART) * sizeof(int), stream);

    // ---- CSR build ----
    bucket_k<<<NBLK, 256, 0, stream>>>(src, dst, bcur, bpk);
    build_k<<<NPART, 256, 0, stream>>>(bcur, bpk, rowptr, csr, perm);

    // ---- layer 1 (input dim 2) -> stats[0] ----
    gmlp1_k<<<(NN + 63) / 64, 128, 0, stream>>>(x, perm, rowptr, csr,
                                                w1_in, b1_in, w1_out, b1_out, bufA, stats);

    // ---- layers 2..5 (input dim 32); BN(j) recomputed in-block ----
    const unsigned short* cur = bufA;
    unsigned short* nxt = bufB;
    for (int j = 0; j < 4; j++) {
        gmlp32_k<<<(NN + 63) / 64, 128, 0, stream>>>(cur, perm, stats + j * 64,
                                              gamma + j * 32, beta + j * 32,
                                              rowptr, csr,
                                              ws_in + j * 1024, bs_in + j * 32,
                                              ws_out + j * 1024, bs_out + j * 32,
                                              nxt, stats + (j + 1) * 64);
        unsigned short* tmp = (unsigned short*)cur; cur = nxt; nxt = tmp;
    }

    // ---- pool (BN(4) in-block) + head ----
    pool_seg_k<<<NG, 256, 0, stream>>>(cur, stats + 4 * 64,
                                       gamma + 4 * 32, beta + 4 * 32, batch, g);
    head_k<<<1, 256, 0, stream>>>(g, fc1w, fc1b, fc2w, fc2b, out);
}

// Round 15
// 469.804 us; speedup vs baseline: 1.0163x; 1.0163x over previous
//
#include <hip/hip_runtime.h>
#include <math.h>

#define NN 100000
#define NE 1600000
#define NG 256
#define NPART 200
#define PS 500                        // nodes per partition (9 bits)
#define CAP 9000                      // bucket capacity (mean 8000, +11 sigma)
#define EPB 2048                      // edges per bucket_k block
#define NBLK ((NE + EPB - 1) / EPB)   // 782
#define DEGB 64                       // degree bins for counting sort
static constexpr float BN_EPS = 1e-5f;

// ---- fp16 helpers (HW RNE via v_cvt) ----
__device__ inline float h2f(unsigned short u) {
    _Float16 h; __builtin_memcpy(&h, &u, 2); return (float)h;
}
__device__ inline unsigned short f2h(float f) {
    _Float16 h = (_Float16)f; unsigned short u; __builtin_memcpy(&u, &h, 2); return u;
}
__device__ inline unsigned int pack2(float a, float b) {
    return (unsigned int)f2h(a) | ((unsigned int)f2h(b) << 16);
}

// ======= CSR stage 1: bucket edges by dst partition; packed u32 payload ======
__global__ __launch_bounds__(256) void bucket_k(const int* __restrict__ src,
                                                const int* __restrict__ dst,
                                                int* __restrict__ bcur,
                                                unsigned int* __restrict__ bpk) {
    __shared__ int cnt[NPART];
    __shared__ int base[NPART];
    int t = threadIdx.x;
    for (int i = t; i < NPART; i += 256) cnt[i] = 0;
    __syncthreads();
    int eb = blockIdx.x * EPB + t * 8;   // all-or-nothing (tail is 64x8)
    bool act = eb < NE;
    int myp[8], myr[8];
    unsigned int pk[8];
    if (act) {
        int4 d0 = *reinterpret_cast<const int4*>(dst + eb);
        int4 d1 = *reinterpret_cast<const int4*>(dst + eb + 4);
        int4 s0 = *reinterpret_cast<const int4*>(src + eb);
        int4 s1 = *reinterpret_cast<const int4*>(src + eb + 4);
        int dd[8] = {d0.x,d0.y,d0.z,d0.w,d1.x,d1.y,d1.z,d1.w};
        int ss[8] = {s0.x,s0.y,s0.z,s0.w,s1.x,s1.y,s1.z,s1.w};
        #pragma unroll
        for (int i = 0; i < 8; i++) {
            int p = dd[i] / PS;
            myp[i] = p;
            pk[i] = ((unsigned int)ss[i] << 9) | (unsigned int)(dd[i] - p * PS);
            myr[i] = atomicAdd(&cnt[p], 1);
        }
    }
    __syncthreads();
    for (int i = t; i < NPART; i += 256)
        base[i] = cnt[i] ? atomicAdd(&bcur[i], cnt[i]) : 0;
    __syncthreads();
    if (act) {
        #pragma unroll
        for (int i = 0; i < 8; i++)
            bpk[myp[i] * CAP + base[myp[i]] + myr[i]] = pk[i];
    }
}

// ==== CSR stage 2: hist + scan + partition-local deg-sort perm + place =======
__global__ __launch_bounds__(256) void build_k(const int* __restrict__ bcur,
                                               const unsigned int* __restrict__ bpk,
                                               int* __restrict__ rowptr,
                                               int* __restrict__ csr,
                                               int* __restrict__ perm) {
    __shared__ int hist[PS];          // histogram -> cursor
    __shared__ int allc[NPART];
    __shared__ int psum[256];
    __shared__ int bc[DEGB];
    int p = blockIdx.x, t = threadIdx.x;
    int lo = p * PS;
    if (t < NPART) allc[t] = bcur[t];
    for (int i = t; i < PS; i += 256) hist[i] = 0;
    if (t < DEGB) bc[t] = 0;
    __syncthreads();
    int base = 0;
    for (int q = 0; q < p; q++) base += allc[q];
    int cnt = allc[p];
    const unsigned int* bp = bpk + p * CAP;
    const uint4* bp4 = reinterpret_cast<const uint4*>(bp);
    int n4 = cnt >> 2;
    for (int i = t; i < n4; i += 256) {
        uint4 v = bp4[i];
        atomicAdd(&hist[v.x & 511u], 1);
        atomicAdd(&hist[v.y & 511u], 1);
        atomicAdd(&hist[v.z & 511u], 1);
        atomicAdd(&hist[v.w & 511u], 1);
    }
    for (int i = 4 * n4 + t; i < cnt; i += 256) atomicAdd(&hist[bp[i] & 511u], 1);
    __syncthreads();
    int j0 = t * 2;
    int d0v = 0, d1v = 0, tsum = 0;
    if (j0 < PS) {
        d0v = hist[j0]; d1v = hist[j0 + 1];
        tsum = d0v + d1v;
        atomicAdd(&bc[d0v < DEGB ? d0v : DEGB - 1], 1);
        atomicAdd(&bc[d1v < DEGB ? d1v : DEGB - 1], 1);
    }
    psum[t] = tsum;
    __syncthreads();
    for (int off = 1; off < 256; off <<= 1) {
        int v = (t >= off) ? psum[t - off] : 0;
        __syncthreads();
        psum[t] += v;
        __syncthreads();
    }
    int texcl = psum[t] - tsum;
    if (j0 < PS) {
        int run = base + texcl;
        hist[j0] = run; rowptr[lo + j0] = run; run += d0v;
        hist[j0 + 1] = run; rowptr[lo + j0 + 1] = run; run += d1v;
    }
    if (p == NPART - 1 && t == 0) rowptr[NN] = base + cnt;
    __syncthreads();
    if (t == 0) {
        int run = 0;
        #pragma unroll
        for (int b = 0; b < DEGB; b++) { int c = bc[b]; bc[b] = run; run += c; }
    }
    __syncthreads();
    if (j0 < PS) {
        int r0 = atomicAdd(&bc[d0v < DEGB ? d0v : DEGB - 1], 1);
        perm[lo + r0] = lo + j0;
        int r1 = atomicAdd(&bc[d1v < DEGB ? d1v : DEGB - 1], 1);
        perm[lo + r1] = lo + j0 + 1;
    }
    __syncthreads();
    for (int i = t; i < n4; i += 256) {
        uint4 v = bp4[i];
        csr[atomicAdd(&hist[v.x & 511u], 1)] = v.x >> 9;
        csr[atomicAdd(&hist[v.y & 511u], 1)] = v.y >> 9;
        csr[atomicAdd(&hist[v.z & 511u], 1)] = v.z >> 9;
        csr[atomicAdd(&hist[v.w & 511u], 1)] = v.w >> 9;
    }
    for (int i = 4 * n4 + t; i < cnt; i += 256)
        csr[atomicAdd(&hist[bp[i] & 511u], 1)] = bp[i] >> 9;
}

// ====== layer 1: 256 threads = 128 nodes x 2 lanes; writes split z ==========
__global__ __launch_bounds__(256) void gmlp1_k(
        const float* __restrict__ x, const int* __restrict__ perm,
        const int* __restrict__ rowptr, const int* __restrict__ csr,
        const float* __restrict__ w_in, const float* __restrict__ b_in,
        const float* __restrict__ w_out, const float* __restrict__ b_out,
        unsigned short* __restrict__ zlo, unsigned short* __restrict__ zhi,
        float* __restrict__ stats) {
    __shared__ float lwi[64], lbi[32], lwo[1024], lbo[32];
    __shared__ float zin[128][33];
    int t = threadIdx.x;
    int n = t >> 1, q = t & 1, c0 = q * 16;
    for (int i = t; i < 1024; i += 256) lwo[i] = w_out[i];
    if (t < 64) lwi[t] = w_in[t];
    if (t < 32) { lbi[t] = b_in[t]; lbo[t] = b_out[t]; }
    __syncthreads();
    int gid = blockIdx.x * 128 + n;
    bool act = gid < NN;
    int node = act ? perm[gid] : 0;
    float h0 = 0.f, h1 = 0.f;
    if (act) {
        int rs = rowptr[node], re = rowptr[node + 1];
        if (q == 0) {
            float2 self = *reinterpret_cast<const float2*>(x + 2 * (size_t)node);
            h0 = self.x; h1 = self.y;
        }
        float g0 = 0.f, g1 = 0.f;
        int k = rs + q;
        for (; k + 6 < re; k += 8) {
            int s0 = csr[k], s1 = csr[k + 2], s2 = csr[k + 4], s3 = csr[k + 6];
            float2 v0 = *reinterpret_cast<const float2*>(x + 2 * (size_t)s0);
            float2 v1 = *reinterpret_cast<const float2*>(x + 2 * (size_t)s1);
            float2 v2 = *reinterpret_cast<const float2*>(x + 2 * (size_t)s2);
            float2 v3 = *reinterpret_cast<const float2*>(x + 2 * (size_t)s3);
            h0 += v0.x + v2.x; h1 += v0.y + v2.y;
            g0 += v1.x + v3.x; g1 += v1.y + v3.y;
        }
        for (; k < re; k += 2) {
            int s = csr[k];
            float2 v = *reinterpret_cast<const float2*>(x + 2 * (size_t)s);
            h0 += v.x; h1 += v.y;
        }
        h0 += g0; h1 += g1;
    }
    h0 += __shfl_xor(h0, 1);
    h1 += __shfl_xor(h1, 1);
    float y[16];
    #pragma unroll
    for (int j = 0; j < 16; j++) {
        float a = lbi[c0 + j] + h0 * lwi[c0 + j] + h1 * lwi[32 + c0 + j];
        y[j] = a > 0.f ? a : 0.f;
    }
    #pragma unroll
    for (int j = 0; j < 16; j++) zin[n][c0 + j] = act ? y[j] : 0.f;
    __syncthreads();
    float o[16];
    #pragma unroll
    for (int j = 0; j < 16; j++) o[j] = lbo[c0 + j];
    #pragma unroll
    for (int c = 0; c < 32; c++) {
        float yv = zin[n][c];
        #pragma unroll
        for (int j = 0; j < 16; j++) o[j] += yv * lwo[c * 32 + c0 + j];
    }
    #pragma unroll
    for (int j = 0; j < 16; j++) o[j] = o[j] > 0.f ? o[j] : 0.f;
    if (act) {
        unsigned short* zo = (q ? zhi : zlo) + (size_t)node * 16;
        uint4 wa, wb;
        wa.x = pack2(o[0], o[1]);   wa.y = pack2(o[2], o[3]);
        wa.z = pack2(o[4], o[5]);   wa.w = pack2(o[6], o[7]);
        wb.x = pack2(o[8], o[9]);   wb.y = pack2(o[10], o[11]);
        wb.z = pack2(o[12], o[13]); wb.w = pack2(o[14], o[15]);
        *reinterpret_cast<uint4*>(zo) = wa;
        *reinterpret_cast<uint4*>(zo + 8) = wb;
    }
    __syncthreads();
    #pragma unroll
    for (int j = 0; j < 16; j++) zin[n][c0 + j] = act ? o[j] : 0.f;
    __syncthreads();
    if (t < 32) {
        float s = 0.f, sq = 0.f;
        for (int nn = 0; nn < 128; nn++) {
            float v = zin[nn][t];
            s += v; sq += v * v;
        }
        atomicAdd(&stats[t], s);
        atomicAdd(&stats[32 + t], sq);
    }
}

// ===== gather pass over ONE 3.2MB half-buffer (L2-resident per XCD) =========
// 256 threads = 128 nodes x 2 lanes; lane owns 8 channels (one 16B load/row).
// No LDS, no barriers -> max occupancy. agg = sum of neighbor half-rows (fp32).
__global__ __launch_bounds__(256) void gather_k(
        const unsigned short* __restrict__ zh, const int* __restrict__ perm,
        const int* __restrict__ rowptr, const int* __restrict__ csr,
        float* __restrict__ agg) {
    int t = threadIdx.x;
    int n = t >> 1, q = t & 1, c0 = q * 8;
    int gid = blockIdx.x * 128 + n;
    if (gid >= NN) return;
    int node = perm[gid];
    int rs = rowptr[node], re = rowptr[node + 1];
    float a[8], b[8];
    #pragma unroll
    for (int j = 0; j < 8; j++) { a[j] = 0.f; b[j] = 0.f; }
    int k = rs;
    for (; k + 4 <= re; k += 4) {
        int s0 = csr[k], s1 = csr[k + 1], s2 = csr[k + 2], s3 = csr[k + 3];
        uint4 v0 = *reinterpret_cast<const uint4*>(zh + (size_t)s0 * 16 + c0);
        uint4 v1 = *reinterpret_cast<const uint4*>(zh + (size_t)s1 * 16 + c0);
        uint4 v2 = *reinterpret_cast<const uint4*>(zh + (size_t)s2 * 16 + c0);
        uint4 v3 = *reinterpret_cast<const uint4*>(zh + (size_t)s3 * 16 + c0);
        const unsigned short* p0 = reinterpret_cast<const unsigned short*>(&v0);
        const unsigned short* p1 = reinterpret_cast<const unsigned short*>(&v1);
        const unsigned short* p2 = reinterpret_cast<const unsigned short*>(&v2);
        const unsigned short* p3 = reinterpret_cast<const unsigned short*>(&v3);
        #pragma unroll
        for (int j = 0; j < 8; j++) {
            a[j] += h2f(p0[j]) + h2f(p2[j]);
            b[j] += h2f(p1[j]) + h2f(p3[j]);
        }
    }
    for (; k < re; k++) {
        int s = csr[k];
        uint4 v = *reinterpret_cast<const uint4*>(zh + (size_t)s * 16 + c0);
        const unsigned short* pp = reinterpret_cast<const unsigned short*>(&v);
        #pragma unroll
        for (int j = 0; j < 8; j++) a[j] += h2f(pp[j]);
    }
    #pragma unroll
    for (int j = 0; j < 8; j++) a[j] += b[j];
    float* ap = agg + (size_t)node * 16 + c0;
    *reinterpret_cast<float4*>(ap) = make_float4(a[0], a[1], a[2], a[3]);
    *reinterpret_cast<float4*>(ap + 4) = make_float4(a[4], a[5], a[6], a[7]);
}

// ===== dense MLP pass: natural order, coalesced; BN-fold + 2 GEMMs + stats ===
__global__ __launch_bounds__(256) void mlp_k(
        const unsigned short* __restrict__ zlo, const unsigned short* __restrict__ zhi,
        const float* __restrict__ agglo, const float* __restrict__ agghi,
        const int* __restrict__ rowptr,
        const float* __restrict__ statsIn,
        const float* __restrict__ gamma, const float* __restrict__ beta,
        const float* __restrict__ w_in, const float* __restrict__ b_in,
        const float* __restrict__ w_out, const float* __restrict__ b_out,
        unsigned short* __restrict__ zloO, unsigned short* __restrict__ zhiO,
        float* __restrict__ statsOut) {
    __shared__ float lwi[1024], lwo[1024], lbi[32], lbo[32], lsc[64];
    __shared__ float zin[128][33];
    int t = threadIdx.x;
    int n = t >> 1, q = t & 1, c0 = q * 16;
    for (int i = t; i < 1024; i += 256) { lwi[i] = w_in[i]; lwo[i] = w_out[i]; }
    if (t < 32) {
        lbi[t] = b_in[t]; lbo[t] = b_out[t];
        float mean = statsIn[t] * (1.f / NN);
        float var  = statsIn[32 + t] * (1.f / NN) - mean * mean;
        float scale = gamma[t] * rsqrtf(var + BN_EPS);
        lsc[t] = scale;
        lsc[32 + t] = beta[t] - mean * scale;
    }
    __syncthreads();
    int node = blockIdx.x * 128 + n;      // natural order
    bool act = node < NN;
    float v[16];
    float cntf = 0.f;
    if (act) {
        const unsigned short* zs = (q ? zhi : zlo) + (size_t)node * 16;
        uint4 sa = *reinterpret_cast<const uint4*>(zs);
        uint4 sb = *reinterpret_cast<const uint4*>(zs + 8);
        const unsigned short* pa = reinterpret_cast<const unsigned short*>(&sa);
        const unsigned short* pb = reinterpret_cast<const unsigned short*>(&sb);
        const float* ag = (q ? agghi : agglo) + (size_t)node * 16;
        float4 a0 = *reinterpret_cast<const float4*>(ag);
        float4 a1 = *reinterpret_cast<const float4*>(ag + 4);
        float4 a2 = *reinterpret_cast<const float4*>(ag + 8);
        float4 a3 = *reinterpret_cast<const float4*>(ag + 12);
        v[0] = h2f(pa[0]) + a0.x; v[1] = h2f(pa[1]) + a0.y;
        v[2] = h2f(pa[2]) + a0.z; v[3] = h2f(pa[3]) + a0.w;
        v[4] = h2f(pa[4]) + a1.x; v[5] = h2f(pa[5]) + a1.y;
        v[6] = h2f(pa[6]) + a1.z; v[7] = h2f(pa[7]) + a1.w;
        v[8]  = h2f(pb[0]) + a2.x; v[9]  = h2f(pb[1]) + a2.y;
        v[10] = h2f(pb[2]) + a2.z; v[11] = h2f(pb[3]) + a2.w;
        v[12] = h2f(pb[4]) + a3.x; v[13] = h2f(pb[5]) + a3.y;
        v[14] = h2f(pb[6]) + a3.z; v[15] = h2f(pb[7]) + a3.w;
        cntf = (float)(rowptr[node + 1] - rowptr[node] + 1);
    } else {
        #pragma unroll
        for (int j = 0; j < 16; j++) v[j] = 0.f;
    }
    #pragma unroll
    for (int j = 0; j < 16; j++)
        zin[n][c0 + j] = act ? (v[j] * lsc[c0 + j] + cntf * lsc[32 + c0 + j]) : 0.f;
    __syncthreads();
    float y[16];
    #pragma unroll
    for (int j = 0; j < 16; j++) y[j] = lbi[c0 + j];
    #pragma unroll
    for (int c = 0; c < 32; c++) {
        float zv = zin[n][c];
        #pragma unroll
        for (int j = 0; j < 16; j++) y[j] += zv * lwi[c * 32 + c0 + j];
    }
    #pragma unroll
    for (int j = 0; j < 16; j++) y[j] = y[j] > 0.f ? y[j] : 0.f;
    __syncthreads();
    #pragma unroll
    for (int j = 0; j < 16; j++) zin[n][c0 + j] = y[j];
    __syncthreads();
    float o[16];
    #pragma unroll
    for (int j = 0; j < 16; j++) o[j] = lbo[c0 + j];
    #pragma unroll
    for (int c = 0; c < 32; c++) {
        float yv = zin[n][c];
        #pragma unroll
        for (int j = 0; j < 16; j++) o[j] += yv * lwo[c * 32 + c0 + j];
    }
    #pragma unroll
    for (int j = 0; j < 16; j++) o[j] = o[j] > 0.f ? o[j] : 0.f;
    if (act) {
        unsigned short* zo = (q ? zhiO : zloO) + (size_t)node * 16;
        uint4 wa, wb;
        wa.x = pack2(o[0], o[1]);   wa.y = pack2(o[2], o[3]);
        wa.z = pack2(o[4], o[5]);   wa.w = pack2(o[6], o[7]);
        wb.x = pack2(o[8], o[9]);   wb.y = pack2(o[10], o[11]);
        wb.z = pack2(o[12], o[13]); wb.w = pack2(o[14], o[15]);
        *reinterpret_cast<uint4*>(zo) = wa;
        *reinterpret_cast<uint4*>(zo + 8) = wb;
    }
    __syncthreads();
    #pragma unroll
    for (int j = 0; j < 16; j++) zin[n][c0 + j] = act ? o[j] : 0.f;
    __syncthreads();
    if (t < 32) {
        float s = 0.f, sq = 0.f;
        for (int nn = 0; nn < 128; nn++) {
            float vv = zin[nn][t];
            s += vv; sq += vv * vv;
        }
        atomicAdd(&statsOut[t], s);
        atomicAdd(&statsOut[32 + t], sq);
    }
}

// ====== pool: batch is SORTED -> one block per graph, binary search ======
__global__ __launch_bounds__(256) void pool_seg_k(
        const unsigned short* __restrict__ zlo, const unsigned short* __restrict__ zhi,
        const float* __restrict__ statsIn,
        const float* __restrict__ gamma, const float* __restrict__ beta,
        const int* __restrict__ batch, float* __restrict__ g) {
    __shared__ float lsc[64];
    __shared__ float part[32][33];
    int t = threadIdx.x, slot = t >> 3, q = t & 7, c0 = q * 4;
    int gr = blockIdx.x;
    if (t < 32) {
        float mean = statsIn[t] * (1.f / NN);
        float var  = statsIn[32 + t] * (1.f / NN) - mean * mean;
        float scale = gamma[t] * rsqrtf(var + BN_EPS);
        lsc[t] = scale;
        lsc[32 + t] = beta[t] - mean * scale;
    }
    int lo = 0, hi = NN;
    while (lo < hi) { int mid = (lo + hi) >> 1; if (batch[mid] < gr) lo = mid + 1; else hi = mid; }
    int start = lo;
    hi = NN;
    while (lo < hi) { int mid = (lo + hi) >> 1; if (batch[mid] < gr + 1) lo = mid + 1; else hi = mid; }
    int end = lo;
    const unsigned short* zb = (c0 < 16) ? zlo : zhi;
    int coff = (c0 < 16) ? c0 : (c0 - 16);
    float a0 = 0.f, a1 = 0.f, a2 = 0.f, a3 = 0.f;
    for (int i = start + slot; i < end; i += 32) {
        ushort4 v = *reinterpret_cast<const ushort4*>(zb + (size_t)i * 16 + coff);
        a0 += h2f(v.x); a1 += h2f(v.y); a2 += h2f(v.z); a3 += h2f(v.w);
    }
    part[slot][c0+0] = a0; part[slot][c0+1] = a1;
    part[slot][c0+2] = a2; part[slot][c0+3] = a3;
    __syncthreads();
    if (t < 32) {
        float s = 0.f;
        for (int sl = 0; sl < 32; sl++) s += part[sl][t];
        float cnt = (float)(end - start);
        g[(size_t)gr * 32 + t] = s * lsc[t] + cnt * lsc[32 + t];
    }
}

// ---------------- head: fc1 -> relu -> fc2 -> log_softmax ----------------
__global__ __launch_bounds__(256) void head_k(
        const float* __restrict__ g,
        const float* __restrict__ fc1w, const float* __restrict__ fc1b,
        const float* __restrict__ fc2w, const float* __restrict__ fc2b,
        float* __restrict__ out) {
    __shared__ float lw1[1024], lb1[32], lw2[64], lb2[2];
    int t = threadIdx.x;
    for (int i = t; i < 1024; i += 256) lw1[i] = fc1w[i];
    if (t < 32) lb1[t] = fc1b[t];
    if (t < 64) lw2[t] = fc2w[t];
    if (t < 2) lb2[t] = fc2b[t];
    __syncthreads();
    float gv[32];
    #pragma unroll
    for (int c = 0; c < 32; c++) gv[c] = g[(size_t)t * 32 + c];
    float o0 = lb2[0], o1 = lb2[1];
    #pragma unroll 4
    for (int k = 0; k < 32; k++) {
        float a = lb1[k];
        #pragma unroll
        for (int c = 0; c < 32; c++) a += gv[c] * lw1[c * 32 + k];
        a = a > 0.f ? a : 0.f;
        o0 += a * lw2[k * 2 + 0];
        o1 += a * lw2[k * 2 + 1];
    }
    float m = fmaxf(o0, o1);
    float lse = m + logf(expf(o0 - m) + expf(o1 - m));
    out[t * 2 + 0] = o0 - lse;
    out[t * 2 + 1] = o1 - lse;
}

extern "C" void kernel_launch(void* const* d_in, const int* in_sizes, int n_in,
                              void* d_out, int out_size, void* d_ws, size_t ws_size,
                              hipStream_t stream) {
    const float* x      = (const float*)d_in[0];
    const int*   ei     = (const int*)d_in[1];
    const int*   src    = ei;
    const int*   dst    = ei + NE;
    const int*   batch  = (const int*)d_in[2];
    const float* w1_in  = (const float*)d_in[3];
    const float* b1_in  = (const float*)d_in[4];
    const float* w1_out = (const float*)d_in[5];
    const float* b1_out = (const float*)d_in[6];
    const float* ws_in  = (const float*)d_in[7];
    const float* bs_in  = (const float*)d_in[8];
    const float* ws_out = (const float*)d_in[9];
    const float* bs_out = (const float*)d_in[10];
    const float* gamma  = (const float*)d_in[11];
    const float* beta   = (const float*)d_in[12];
    const float* fc1w   = (const float*)d_in[13];
    const float* fc1b   = (const float*)d_in[14];
    const float* fc2w   = (const float*)d_in[15];
    const float* fc2b   = (const float*)d_in[16];
    float* out = (float*)d_out;

    // ---- workspace layout (16B alignment maintained) ----
    unsigned short* zloA = (unsigned short*)d_ws;        // NN*16 fp16 (3.2MB)
    unsigned short* zhiA = zloA + (size_t)NN * 16;
    unsigned short* zloB = zhiA + (size_t)NN * 16;
    unsigned short* zhiB = zloB + (size_t)NN * 16;
    float* agglo  = (float*)(zhiB + (size_t)NN * 16);    // NN*16 fp32 (6.4MB)
    float* agghi  = agglo + (size_t)NN * 16;             // NN*16 fp32
    float* stats  = agghi + (size_t)NN * 16;             // 5*64 (zeroed)
    int*   bcur   = (int*)(stats + 5 * 64);              // NPART (zeroed, adjacent)
    float* g      = (float*)(bcur + NPART);              // NG*32
    int*   perm   = (int*)(g + (size_t)NG * 32);         // NN
    int*   rowptr = perm + NN;                           // NN+4
    int*   csr    = rowptr + NN + 4;                     // NE
    unsigned int* bpk = (unsigned int*)(csr + NE);       // NPART*CAP

    // ---- zero stats + bucket cursors in one memset ----
    hipMemsetAsync(stats, 0, (size_t)(5 * 64 + NPART) * sizeof(int), stream);

    // ---- CSR build ----
    bucket_k<<<NBLK, 256, 0, stream>>>(src, dst, bcur, bpk);
    build_k<<<NPART, 256, 0, stream>>>(bcur, bpk, rowptr, csr, perm);

    // ---- layer 1 (input dim 2) -> stats[0], split z out ----
    gmlp1_k<<<(NN + 127) / 128, 256, 0, stream>>>(x, perm, rowptr, csr,
                                                  w1_in, b1_in, w1_out, b1_out,
                                                  zloA, zhiA, stats);

    // ---- layers 2..5: two L2-resident gather passes + dense MLP ----
    unsigned short *clo = zloA, *chi = zhiA, *nlo = zloB, *nhi = zhiB;
    for (int j = 0; j < 4; j++) {
        gather_k<<<(NN + 127) / 128, 256, 0, stream>>>(clo, perm, rowptr, csr, agglo);
        gather_k<<<(NN + 127) / 128, 256, 0, stream>>>(chi, perm, rowptr, csr, agghi);
        mlp_k<<<(NN + 127) / 128, 256, 0, stream>>>(clo, chi, agglo, agghi, rowptr,
                                                    stats + j * 64,
                                                    gamma + j * 32, beta + j * 32,
                                                    ws_in + j * 1024, bs_in + j * 32,
                                                    ws_out + j * 1024, bs_out + j * 32,
                                                    nlo, nhi, stats + (j + 1) * 64);
        unsigned short* tl = clo; clo = nlo; nlo = tl;
        unsigned short* th = chi; chi = nhi; nhi = th;
    }

    // ---- pool (BN(4) in-block) + head ----
    pool_seg_k<<<NG, 256, 0, stream>>>(clo, chi, stats + 4 * 64,
                                       gamma + 4 * 32, beta + 4 * 32, batch, g);
    head_k<<<1, 256, 0, stream>>>(g, fc1w, fc1b, fc2w, fc2b, out);
}

// Round 16
// 447.854 us; speedup vs baseline: 1.0661x; 1.0490x over previous
//
#include <hip/hip_runtime.h>
#include <math.h>

#define NN 100000
#define NE 1600000
#define NG 256
#define NPART 400
#define PS 250                        // nodes per partition (8 bits)
#define CAP 4500                      // bucket capacity (mean 4000, +8 sigma)
#define EPB 2048                      // edges per bucket_k block
#define NBLK ((NE + EPB - 1) / EPB)   // 782
#define DEGB 64                       // degree bins for counting sort
static constexpr float BN_EPS = 1e-5f;

// ---- fp16 helpers (HW RNE via v_cvt) ----
__device__ inline float h2f(unsigned short u) {
    _Float16 h; __builtin_memcpy(&h, &u, 2); return (float)h;
}
__device__ inline unsigned short f2h(float f) {
    _Float16 h = (_Float16)f; unsigned short u; __builtin_memcpy(&u, &h, 2); return u;
}
__device__ inline unsigned int pack2(float a, float b) {
    return (unsigned int)f2h(a) | ((unsigned int)f2h(b) << 16);
}

// ======= CSR stage 1: bucket edges by dst partition; packed u32 payload ======
// pk = (src << 8) | (dst - p*PS);  src < 2^17, dst-lo < 256
__global__ __launch_bounds__(256) void bucket_k(const int* __restrict__ src,
                                                const int* __restrict__ dst,
                                                int* __restrict__ bcur,
                                                unsigned int* __restrict__ bpk) {
    __shared__ int cnt[NPART];
    __shared__ int base[NPART];
    int t = threadIdx.x;
    for (int i = t; i < NPART; i += 256) cnt[i] = 0;
    __syncthreads();
    int eb = blockIdx.x * EPB + t * 8;   // all-or-nothing (tail is 64x8)
    bool act = eb < NE;
    int myp[8], myr[8];
    unsigned int pk[8];
    if (act) {
        int4 d0 = *reinterpret_cast<const int4*>(dst + eb);
        int4 d1 = *reinterpret_cast<const int4*>(dst + eb + 4);
        int4 s0 = *reinterpret_cast<const int4*>(src + eb);
        int4 s1 = *reinterpret_cast<const int4*>(src + eb + 4);
        int dd[8] = {d0.x,d0.y,d0.z,d0.w,d1.x,d1.y,d1.z,d1.w};
        int ss[8] = {s0.x,s0.y,s0.z,s0.w,s1.x,s1.y,s1.z,s1.w};
        #pragma unroll
        for (int i = 0; i < 8; i++) {
            int p = dd[i] / PS;
            myp[i] = p;
            pk[i] = ((unsigned int)ss[i] << 8) | (unsigned int)(dd[i] - p * PS);
            myr[i] = atomicAdd(&cnt[p], 1);
        }
    }
    __syncthreads();
    for (int i = t; i < NPART; i += 256)
        base[i] = cnt[i] ? atomicAdd(&bcur[i], cnt[i]) : 0;
    __syncthreads();
    if (act) {
        #pragma unroll
        for (int i = 0; i < 8; i++)
            bpk[myp[i] * CAP + base[myp[i]] + myr[i]] = pk[i];
    }
}

// ==== CSR stage 2: hist + scan + partition-local deg-sort perm + place =======
__global__ __launch_bounds__(256) void build_k(const int* __restrict__ bcur,
                                               const unsigned int* __restrict__ bpk,
                                               int* __restrict__ rowptr,
                                               int* __restrict__ csr,
                                               int* __restrict__ perm) {
    __shared__ int hist[PS];          // histogram -> cursor
    __shared__ int allc[NPART];
    __shared__ int psum[256];
    __shared__ int bc[DEGB];
    int p = blockIdx.x, t = threadIdx.x;
    int lo = p * PS;
    for (int i = t; i < NPART; i += 256) allc[i] = bcur[i];
    for (int i = t; i < PS; i += 256) hist[i] = 0;
    if (t < DEGB) bc[t] = 0;
    __syncthreads();
    int base = 0;
    for (int q = 0; q < p; q++) base += allc[q];
    int cnt = allc[p];
    const unsigned int* bp = bpk + p * CAP;
    const uint4* bp4 = reinterpret_cast<const uint4*>(bp);
    int n4 = cnt >> 2;
    for (int i = t; i < n4; i += 256) {
        uint4 v = bp4[i];
        atomicAdd(&hist[v.x & 255u], 1);
        atomicAdd(&hist[v.y & 255u], 1);
        atomicAdd(&hist[v.z & 255u], 1);
        atomicAdd(&hist[v.w & 255u], 1);
    }
    for (int i = 4 * n4 + t; i < cnt; i += 256) atomicAdd(&hist[bp[i] & 255u], 1);
    __syncthreads();
    // thread t owns node t (t < PS)
    int dv = 0, tsum = 0;
    if (t < PS) {
        dv = hist[t];
        tsum = dv;
        atomicAdd(&bc[dv < DEGB ? dv : DEGB - 1], 1);
    }
    psum[t] = tsum;
    __syncthreads();
    for (int off = 1; off < 256; off <<= 1) {
        int v = (t >= off) ? psum[t - off] : 0;
        __syncthreads();
        psum[t] += v;
        __syncthreads();
    }
    int texcl = psum[t] - tsum;
    if (t < PS) {
        int run = base + texcl;
        hist[t] = run;
        rowptr[lo + t] = run;
    }
    if (p == NPART - 1 && t == 0) rowptr[NN] = base + cnt;
    __syncthreads();
    if (t == 0) {
        int run = 0;
        #pragma unroll
        for (int b = 0; b < DEGB; b++) { int c = bc[b]; bc[b] = run; run += c; }
    }
    __syncthreads();
    if (t < PS) {
        int r = atomicAdd(&bc[dv < DEGB ? dv : DEGB - 1], 1);
        perm[lo + r] = lo + t;    // partition-local degree sort (locality kept)
    }
    __syncthreads();
    for (int i = t; i < n4; i += 256) {
        uint4 v = bp4[i];
        csr[atomicAdd(&hist[v.x & 255u], 1)] = v.x >> 8;
        csr[atomicAdd(&hist[v.y & 255u], 1)] = v.y >> 8;
        csr[atomicAdd(&hist[v.z & 255u], 1)] = v.z >> 8;
        csr[atomicAdd(&hist[v.w & 255u], 1)] = v.w >> 8;
    }
    for (int i = 4 * n4 + t; i < cnt; i += 256)
        csr[atomicAdd(&hist[bp[i] & 255u], 1)] = bp[i] >> 8;
}

// ====== layer 1: 128 threads = 64 nodes x 2 lanes, shfl-combined gather ======
__global__ __launch_bounds__(128) void gmlp1_k(
        const float* __restrict__ x, const int* __restrict__ perm,
        const int* __restrict__ rowptr, const int* __restrict__ csr,
        const float* __restrict__ w_in, const float* __restrict__ b_in,
        const float* __restrict__ w_out, const float* __restrict__ b_out,
        unsigned short* __restrict__ zout, float* __restrict__ stats) {
    __shared__ float lwi[64], lbi[32], lwo[1024], lbo[32];
    __shared__ float zin[64][33];
    int t = threadIdx.x;
    int n = t >> 1, q = t & 1, c0 = q * 16;
    for (int i = t; i < 1024; i += 128) lwo[i] = w_out[i];
    if (t < 64) lwi[t] = w_in[t];
    if (t < 32) { lbi[t] = b_in[t]; lbo[t] = b_out[t]; }
    __syncthreads();
    int gid = blockIdx.x * 64 + n;
    bool act = gid < NN;
    int node = act ? perm[gid] : 0;
    float h0 = 0.f, h1 = 0.f;
    if (act) {
        int rs = rowptr[node], re = rowptr[node + 1];
        if (q == 0) {
            float2 self = *reinterpret_cast<const float2*>(x + 2 * (size_t)node);
            h0 = self.x; h1 = self.y;
        }
        float g0 = 0.f, g1 = 0.f;
        int k = rs + q;           // lane q takes every other neighbor
        for (; k + 6 < re; k += 8) {
            int s0 = csr[k], s1 = csr[k + 2], s2 = csr[k + 4], s3 = csr[k + 6];
            float2 v0 = *reinterpret_cast<const float2*>(x + 2 * (size_t)s0);
            float2 v1 = *reinterpret_cast<const float2*>(x + 2 * (size_t)s1);
            float2 v2 = *reinterpret_cast<const float2*>(x + 2 * (size_t)s2);
            float2 v3 = *reinterpret_cast<const float2*>(x + 2 * (size_t)s3);
            h0 += v0.x + v2.x; h1 += v0.y + v2.y;
            g0 += v1.x + v3.x; g1 += v1.y + v3.y;
        }
        for (; k < re; k += 2) {
            int s = csr[k];
            float2 v = *reinterpret_cast<const float2*>(x + 2 * (size_t)s);
            h0 += v.x; h1 += v.y;
        }
        h0 += g0; h1 += g1;
    }
    h0 += __shfl_xor(h0, 1);
    h1 += __shfl_xor(h1, 1);
    float y[16];
    #pragma unroll
    for (int j = 0; j < 16; j++) {
        float a = lbi[c0 + j] + h0 * lwi[c0 + j] + h1 * lwi[32 + c0 + j];
        y[j] = a > 0.f ? a : 0.f;
    }
    #pragma unroll
    for (int j = 0; j < 16; j++) zin[n][c0 + j] = act ? y[j] : 0.f;
    __syncthreads();
    float o[16];
    #pragma unroll
    for (int j = 0; j < 16; j++) o[j] = lbo[c0 + j];
    #pragma unroll
    for (int c = 0; c < 32; c++) {
        float yv = zin[n][c];
        #pragma unroll
        for (int j = 0; j < 16; j++) o[j] += yv * lwo[c * 32 + c0 + j];
    }
    #pragma unroll
    for (int j = 0; j < 16; j++) o[j] = o[j] > 0.f ? o[j] : 0.f;
    if (act) {
        unsigned short* zo = zout + (size_t)node * 32 + c0;
        uint4 wa, wb;
        wa.x = pack2(o[0], o[1]);   wa.y = pack2(o[2], o[3]);
        wa.z = pack2(o[4], o[5]);   wa.w = pack2(o[6], o[7]);
        wb.x = pack2(o[8], o[9]);   wb.y = pack2(o[10], o[11]);
        wb.z = pack2(o[12], o[13]); wb.w = pack2(o[14], o[15]);
        *reinterpret_cast<uint4*>(zo) = wa;
        *reinterpret_cast<uint4*>(zo + 8) = wb;
    }
    __syncthreads();
    #pragma unroll
    for (int j = 0; j < 16; j++) zin[n][c0 + j] = act ? o[j] : 0.f;
    __syncthreads();
    if (t < 32) {
        float s = 0.f, sq = 0.f;
        for (int nn = 0; nn < 64; nn++) {
            float v = zin[nn][t];
            s += v; sq += v * v;
        }
        atomicAdd(&stats[t], s);
        atomicAdd(&stats[32 + t], sq);
    }
}

// ======= heavy layer: 2 lanes/node, 128 nodes/block, 8-row-unrolled gather ===
__global__ __launch_bounds__(256) void gmlp32_k(
        const unsigned short* __restrict__ z, const int* __restrict__ perm,
        const float* __restrict__ statsIn,
        const float* __restrict__ gamma, const float* __restrict__ beta,
        const int* __restrict__ rowptr, const int* __restrict__ csr,
        const float* __restrict__ w_in, const float* __restrict__ b_in,
        const float* __restrict__ w_out, const float* __restrict__ b_out,
        unsigned short* __restrict__ zout, float* __restrict__ statsOut) {
    __shared__ float lwi[1024], lwo[1024], lbi[32], lbo[32], lsc[64];
    __shared__ float zin[128][33];
    int t = threadIdx.x;
    int n = t >> 1, q = t & 1, c0 = q * 16;
    for (int i = t; i < 1024; i += 256) { lwi[i] = w_in[i]; lwo[i] = w_out[i]; }
    if (t < 32) {
        lbi[t] = b_in[t]; lbo[t] = b_out[t];
        float mean = statsIn[t] * (1.f / NN);
        float var  = statsIn[32 + t] * (1.f / NN) - mean * mean;
        float scale = gamma[t] * rsqrtf(var + BN_EPS);
        lsc[t] = scale;
        lsc[32 + t] = beta[t] - mean * scale;
    }
    __syncthreads();
    int gid = blockIdx.x * 128 + n;
    bool act = gid < NN;
    int node = act ? perm[gid] : 0;
    float a[16];
    #pragma unroll
    for (int j = 0; j < 16; j++) a[j] = 0.f;
    float cntf = 0.f;
    if (act) {
        int rs = rowptr[node], re = rowptr[node + 1];
        cntf = (float)(re - rs + 1);
        const unsigned short* zb = z + (size_t)node * 32 + c0;
        uint4 sa = *reinterpret_cast<const uint4*>(zb);
        uint4 sb = *reinterpret_cast<const uint4*>(zb + 8);
        const unsigned short* pa = reinterpret_cast<const unsigned short*>(&sa);
        const unsigned short* pb = reinterpret_cast<const unsigned short*>(&sb);
        #pragma unroll
        for (int j = 0; j < 8; j++) { a[j] = h2f(pa[j]); a[8 + j] = h2f(pb[j]); }
        int k = rs;
        // 8-row unrolled main loop: 16 x uint4 in flight per lane
        for (; k + 8 <= re; k += 8) {
            uint4 va[8], vb[8];
            #pragma unroll
            for (int r = 0; r < 8; r++) {
                const unsigned short* rp = z + (size_t)csr[k + r] * 32 + c0;
                va[r] = *reinterpret_cast<const uint4*>(rp);
                vb[r] = *reinterpret_cast<const uint4*>(rp + 8);
            }
            #pragma unroll
            for (int r = 0; r < 8; r++) {
                const unsigned short* qa = reinterpret_cast<const unsigned short*>(&va[r]);
                const unsigned short* qb = reinterpret_cast<const unsigned short*>(&vb[r]);
                #pragma unroll
                for (int j = 0; j < 8; j++) {
                    a[j]     += h2f(qa[j]);
                    a[8 + j] += h2f(qb[j]);
                }
            }
        }
        for (; k + 4 <= re; k += 4) {
            uint4 va[4], vb[4];
            #pragma unroll
            for (int r = 0; r < 4; r++) {
                const unsigned short* rp = z + (size_t)csr[k + r] * 32 + c0;
                va[r] = *reinterpret_cast<const uint4*>(rp);
                vb[r] = *reinterpret_cast<const uint4*>(rp + 8);
            }
            #pragma unroll
            for (int r = 0; r < 4; r++) {
                const unsigned short* qa = reinterpret_cast<const unsigned short*>(&va[r]);
                const unsigned short* qb = reinterpret_cast<const unsigned short*>(&vb[r]);
                #pragma unroll
                for (int j = 0; j < 8; j++) {
                    a[j]     += h2f(qa[j]);
                    a[8 + j] += h2f(qb[j]);
                }
            }
        }
        for (; k < re; k++) {
            const unsigned short* rp = z + (size_t)csr[k] * 32 + c0;
            uint4 va = *reinterpret_cast<const uint4*>(rp);
            uint4 vb = *reinterpret_cast<const uint4*>(rp + 8);
            const unsigned short* qa = reinterpret_cast<const unsigned short*>(&va);
            const unsigned short* qb = reinterpret_cast<const unsigned short*>(&vb);
            #pragma unroll
            for (int j = 0; j < 8; j++) { a[j] += h2f(qa[j]); a[8 + j] += h2f(qb[j]); }
        }
    }
    #pragma unroll
    for (int j = 0; j < 16; j++)
        zin[n][c0 + j] = act ? (a[j] * lsc[c0 + j] + cntf * lsc[32 + c0 + j]) : 0.f;
    __syncthreads();
    float y[16];
    #pragma unroll
    for (int j = 0; j < 16; j++) y[j] = lbi[c0 + j];
    #pragma unroll
    for (int c = 0; c < 32; c++) {
        float zv = zin[n][c];
        #pragma unroll
        for (int j = 0; j < 16; j++) y[j] += zv * lwi[c * 32 + c0 + j];
    }
    #pragma unroll
    for (int j = 0; j < 16; j++) y[j] = y[j] > 0.f ? y[j] : 0.f;
    __syncthreads();
    #pragma unroll
    for (int j = 0; j < 16; j++) zin[n][c0 + j] = y[j];
    __syncthreads();
    float o[16];
    #pragma unroll
    for (int j = 0; j < 16; j++) o[j] = lbo[c0 + j];
    #pragma unroll
    for (int c = 0; c < 32; c++) {
        float yv = zin[n][c];
        #pragma unroll
        for (int j = 0; j < 16; j++) o[j] += yv * lwo[c * 32 + c0 + j];
    }
    #pragma unroll
    for (int j = 0; j < 16; j++) o[j] = o[j] > 0.f ? o[j] : 0.f;
    if (act) {
        unsigned short* zo = zout + (size_t)node * 32 + c0;
        uint4 wa, wb;
        wa.x = pack2(o[0], o[1]);   wa.y = pack2(o[2], o[3]);
        wa.z = pack2(o[4], o[5]);   wa.w = pack2(o[6], o[7]);
        wb.x = pack2(o[8], o[9]);   wb.y = pack2(o[10], o[11]);
        wb.z = pack2(o[12], o[13]); wb.w = pack2(o[14], o[15]);
        *reinterpret_cast<uint4*>(zo) = wa;
        *reinterpret_cast<uint4*>(zo + 8) = wb;
    }
    __syncthreads();
    #pragma unroll
    for (int j = 0; j < 16; j++) zin[n][c0 + j] = act ? o[j] : 0.f;
    __syncthreads();
    if (t < 32) {
        float s = 0.f, sq = 0.f;
        for (int nn = 0; nn < 128; nn++) {
            float v = zin[nn][t];
            s += v; sq += v * v;
        }
        atomicAdd(&statsOut[t], s);
        atomicAdd(&statsOut[32 + t], sq);
    }
}

// ====== pool: batch is SORTED -> one block per graph, binary search ======
__global__ __launch_bounds__(256) void pool_seg_k(
        const unsigned short* __restrict__ z,
        const float* __restrict__ statsIn,
        const float* __restrict__ gamma, const float* __restrict__ beta,
        const int* __restrict__ batch, float* __restrict__ g) {
    __shared__ float lsc[64];
    __shared__ float part[32][33];
    int t = threadIdx.x, slot = t >> 3, q = t & 7, c0 = q * 4;
    int gr = blockIdx.x;
    if (t < 32) {
        float mean = statsIn[t] * (1.f / NN);
        float var  = statsIn[32 + t] * (1.f / NN) - mean * mean;
        float scale = gamma[t] * rsqrtf(var + BN_EPS);
        lsc[t] = scale;
        lsc[32 + t] = beta[t] - mean * scale;
    }
    int lo = 0, hi = NN;
    while (lo < hi) { int mid = (lo + hi) >> 1; if (batch[mid] < gr) lo = mid + 1; else hi = mid; }
    int start = lo;
    hi = NN;
    while (lo < hi) { int mid = (lo + hi) >> 1; if (batch[mid] < gr + 1) lo = mid + 1; else hi = mid; }
    int end = lo;
    float a0 = 0.f, a1 = 0.f, a2 = 0.f, a3 = 0.f;
    for (int i = start + slot; i < end; i += 32) {
        ushort4 v = *reinterpret_cast<const ushort4*>(z + (size_t)i * 32 + c0);
        a0 += h2f(v.x); a1 += h2f(v.y); a2 += h2f(v.z); a3 += h2f(v.w);
    }
    part[slot][c0+0] = a0; part[slot][c0+1] = a1;
    part[slot][c0+2] = a2; part[slot][c0+3] = a3;
    __syncthreads();
    if (t < 32) {
        float s = 0.f;
        for (int sl = 0; sl < 32; sl++) s += part[sl][t];
        float cnt = (float)(end - start);
        g[(size_t)gr * 32 + t] = s * lsc[t] + cnt * lsc[32 + t];
    }
}

// ---------------- head: fc1 -> relu -> fc2 -> log_softmax ----------------
__global__ __launch_bounds__(256) void head_k(
        const float* __restrict__ g,
        const float* __restrict__ fc1w, const float* __restrict__ fc1b,
        const float* __restrict__ fc2w, const float* __restrict__ fc2b,
        float* __restrict__ out) {
    __shared__ float lw1[1024], lb1[32], lw2[64], lb2[2];
    int t = threadIdx.x;
    for (int i = t; i < 1024; i += 256) lw1[i] = fc1w[i];
    if (t < 32) lb1[t] = fc1b[t];
    if (t < 64) lw2[t] = fc2w[t];
    if (t < 2) lb2[t] = fc2b[t];
    __syncthreads();
    float gv[32];
    #pragma unroll
    for (int c = 0; c < 32; c++) gv[c] = g[(size_t)t * 32 + c];
    float o0 = lb2[0], o1 = lb2[1];
    #pragma unroll 4
    for (int k = 0; k < 32; k++) {
        float a = lb1[k];
        #pragma unroll
        for (int c = 0; c < 32; c++) a += gv[c] * lw1[c * 32 + k];
        a = a > 0.f ? a : 0.f;
        o0 += a * lw2[k * 2 + 0];
        o1 += a * lw2[k * 2 + 1];
    }
    float m = fmaxf(o0, o1);
    float lse = m + logf(expf(o0 - m) + expf(o1 - m));
    out[t * 2 + 0] = o0 - lse;
    out[t * 2 + 1] = o1 - lse;
}

extern "C" void kernel_launch(void* const* d_in, const int* in_sizes, int n_in,
                              void* d_out, int out_size, void* d_ws, size_t ws_size,
                              hipStream_t stream) {
    const float* x      = (const float*)d_in[0];
    const int*   ei     = (const int*)d_in[1];
    const int*   src    = ei;
    const int*   dst    = ei + NE;
    const int*   batch  = (const int*)d_in[2];
    const float* w1_in  = (const float*)d_in[3];
    const float* b1_in  = (const float*)d_in[4];
    const float* w1_out = (const float*)d_in[5];
    const float* b1_out = (const float*)d_in[6];
    const float* ws_in  = (const float*)d_in[7];
    const float* bs_in  = (const float*)d_in[8];
    const float* ws_out = (const float*)d_in[9];
    const float* bs_out = (const float*)d_in[10];
    const float* gamma  = (const float*)d_in[11];
    const float* beta   = (const float*)d_in[12];
    const float* fc1w   = (const float*)d_in[13];
    const float* fc1b   = (const float*)d_in[14];
    const float* fc2w   = (const float*)d_in[15];
    const float* fc2b   = (const float*)d_in[16];
    float* out = (float*)d_out;

    // ---- workspace layout (16B alignment maintained) ----
    unsigned short* bufA = (unsigned short*)d_ws;        // NN*32 fp16
    unsigned short* bufB = bufA + (size_t)NN * 32;       // NN*32 fp16
    float* stats  = (float*)(bufB + (size_t)NN * 32);    // 5*64 (zeroed)
    int*   bcur   = (int*)(stats + 5 * 64);              // NPART (zeroed, adjacent)
    float* g      = (float*)(bcur + NPART);              // NG*32
    int*   perm   = (int*)(g + (size_t)NG * 32);         // NN
    int*   rowptr = perm + NN;                           // NN+4
    int*   csr    = rowptr + NN + 4;                     // NE
    unsigned int* bpk = (unsigned int*)(csr + NE);       // NPART*CAP

    // ---- zero stats + bucket cursors in one memset ----
    hipMemsetAsync(stats, 0, (size_t)(5 * 64 + NPART) * sizeof(int), stream);

    // ---- CSR build ----
    bucket_k<<<NBLK, 256, 0, stream>>>(src, dst, bcur, bpk);
    build_k<<<NPART, 256, 0, stream>>>(bcur, bpk, rowptr, csr, perm);

    // ---- layer 1 (input dim 2) -> stats[0] ----
    gmlp1_k<<<(NN + 63) / 64, 128, 0, stream>>>(x, perm, rowptr, csr,
                                                w1_in, b1_in, w1_out, b1_out, bufA, stats);

    // ---- layers 2..5 (input dim 32); BN(j) recomputed in-block ----
    const unsigned short* cur = bufA;
    unsigned short* nxt = bufB;
    for (int j = 0; j < 4; j++) {
        gmlp32_k<<<(NN + 127) / 128, 256, 0, stream>>>(cur, perm, stats + j * 64,
                                              gamma + j * 32, beta + j * 32,
                                              rowptr, csr,
                                              ws_in + j * 1024, bs_in + j * 32,
                                              ws_out + j * 1024, bs_out + j * 32,
                                              nxt, stats + (j + 1) * 64);
        unsigned short* tmp = (unsigned short*)cur; cur = nxt; nxt = tmp;
    }

    // ---- pool (BN(4) in-block) + head ----
    pool_seg_k<<<NG, 256, 0, stream>>>(cur, stats + 4 * 64,
                                       gamma + 4 * 32, beta + 4 * 32, batch, g);
    head_k<<<1, 256, 0, stream>>>(g, fc1w, fc1b, fc2w, fc2b, out);
}

// Round 17
// 384.588 us; speedup vs baseline: 1.2414x; 1.1645x over previous
//
#include <hip/hip_runtime.h>
#include <math.h>

#define NN 100000
#define NE 1600000
#define NG 256
#define NPART 400
#define PS 250                        // nodes per partition (8 bits)
#define CAP 4500                      // bucket capacity (mean 4000, +8 sigma)
#define EPB 2048                      // edges per bucket_k block
#define NBLK ((NE + EPB - 1) / EPB)   // 782
#define DEGB 64                       // degree bins for counting sort
static constexpr float BN_EPS = 1e-5f;

// ---- fp16 helpers (HW RNE via v_cvt) ----
__device__ inline float h2f(unsigned short u) {
    _Float16 h; __builtin_memcpy(&h, &u, 2); return (float)h;
}
__device__ inline unsigned short f2h(float f) {
    _Float16 h = (_Float16)f; unsigned short u; __builtin_memcpy(&u, &h, 2); return u;
}
__device__ inline unsigned int pack2(float a, float b) {
    return (unsigned int)f2h(a) | ((unsigned int)f2h(b) << 16);
}

// ======= CSR stage 1: bucket edges by dst partition; packed u32 payload ======
// pk = (src << 8) | (dst - p*PS);  src < 2^17, dst-lo < 256
__global__ __launch_bounds__(256) void bucket_k(const int* __restrict__ src,
                                                const int* __restrict__ dst,
                                                int* __restrict__ bcur,
                                                unsigned int* __restrict__ bpk) {
    __shared__ int cnt[NPART];
    __shared__ int base[NPART];
    int t = threadIdx.x;
    for (int i = t; i < NPART; i += 256) cnt[i] = 0;
    __syncthreads();
    int eb = blockIdx.x * EPB + t * 8;   // all-or-nothing (tail is 64x8)
    bool act = eb < NE;
    int myp[8], myr[8];
    unsigned int pk[8];
    if (act) {
        int4 d0 = *reinterpret_cast<const int4*>(dst + eb);
        int4 d1 = *reinterpret_cast<const int4*>(dst + eb + 4);
        int4 s0 = *reinterpret_cast<const int4*>(src + eb);
        int4 s1 = *reinterpret_cast<const int4*>(src + eb + 4);
        int dd[8] = {d0.x,d0.y,d0.z,d0.w,d1.x,d1.y,d1.z,d1.w};
        int ss[8] = {s0.x,s0.y,s0.z,s0.w,s1.x,s1.y,s1.z,s1.w};
        #pragma unroll
        for (int i = 0; i < 8; i++) {
            int p = dd[i] / PS;
            myp[i] = p;
            pk[i] = ((unsigned int)ss[i] << 8) | (unsigned int)(dd[i] - p * PS);
            myr[i] = atomicAdd(&cnt[p], 1);
        }
    }
    __syncthreads();
    for (int i = t; i < NPART; i += 256)
        base[i] = cnt[i] ? atomicAdd(&bcur[i], cnt[i]) : 0;
    __syncthreads();
    if (act) {
        #pragma unroll
        for (int i = 0; i < 8; i++)
            bpk[myp[i] * CAP + base[myp[i]] + myr[i]] = pk[i];
    }
}

// ==== CSR stage 2: hist + scan + partition-local deg-sort perm + place =======
__global__ __launch_bounds__(256) void build_k(const int* __restrict__ bcur,
                                               const unsigned int* __restrict__ bpk,
                                               int* __restrict__ rowptr,
                                               int* __restrict__ csr,
                                               int* __restrict__ perm) {
    __shared__ int hist[PS];          // histogram -> cursor
    __shared__ int allc[NPART];
    __shared__ int psum[256];
    __shared__ int bc[DEGB];
    int p = blockIdx.x, t = threadIdx.x;
    int lo = p * PS;
    for (int i = t; i < NPART; i += 256) allc[i] = bcur[i];
    for (int i = t; i < PS; i += 256) hist[i] = 0;
    if (t < DEGB) bc[t] = 0;
    __syncthreads();
    int base = 0;
    for (int q = 0; q < p; q++) base += allc[q];
    int cnt = allc[p];
    const unsigned int* bp = bpk + p * CAP;
    const uint4* bp4 = reinterpret_cast<const uint4*>(bp);
    int n4 = cnt >> 2;
    for (int i = t; i < n4; i += 256) {
        uint4 v = bp4[i];
        atomicAdd(&hist[v.x & 255u], 1);
        atomicAdd(&hist[v.y & 255u], 1);
        atomicAdd(&hist[v.z & 255u], 1);
        atomicAdd(&hist[v.w & 255u], 1);
    }
    for (int i = 4 * n4 + t; i < cnt; i += 256) atomicAdd(&hist[bp[i] & 255u], 1);
    __syncthreads();
    // thread t owns node t (t < PS)
    int dv = 0, tsum = 0;
    if (t < PS) {
        dv = hist[t];
        tsum = dv;
        atomicAdd(&bc[dv < DEGB ? dv : DEGB - 1], 1);
    }
    psum[t] = tsum;
    __syncthreads();
    for (int off = 1; off < 256; off <<= 1) {
        int v = (t >= off) ? psum[t - off] : 0;
        __syncthreads();
        psum[t] += v;
        __syncthreads();
    }
    int texcl = psum[t] - tsum;
    if (t < PS) {
        int run = base + texcl;
        hist[t] = run;
        rowptr[lo + t] = run;
    }
    if (p == NPART - 1 && t == 0) rowptr[NN] = base + cnt;
    __syncthreads();
    if (t == 0) {
        int run = 0;
        #pragma unroll
        for (int b = 0; b < DEGB; b++) { int c = bc[b]; bc[b] = run; run += c; }
    }
    __syncthreads();
    if (t < PS) {
        int r = atomicAdd(&bc[dv < DEGB ? dv : DEGB - 1], 1);
        perm[lo + r] = lo + t;    // partition-local degree sort (locality kept)
    }
    __syncthreads();
    for (int i = t; i < n4; i += 256) {
        uint4 v = bp4[i];
        csr[atomicAdd(&hist[v.x & 255u], 1)] = v.x >> 8;
        csr[atomicAdd(&hist[v.y & 255u], 1)] = v.y >> 8;
        csr[atomicAdd(&hist[v.z & 255u], 1)] = v.z >> 8;
        csr[atomicAdd(&hist[v.w & 255u], 1)] = v.w >> 8;
    }
    for (int i = 4 * n4 + t; i < cnt; i += 256)
        csr[atomicAdd(&hist[bp[i] & 255u], 1)] = bp[i] >> 8;
}

// ====== layer 1: 256 threads = 128 nodes x 2 lanes, shfl-combined gather =====
__global__ __launch_bounds__(256) void gmlp1_k(
        const float* __restrict__ x, const int* __restrict__ perm,
        const int* __restrict__ rowptr, const int* __restrict__ csr,
        const float* __restrict__ w_in, const float* __restrict__ b_in,
        const float* __restrict__ w_out, const float* __restrict__ b_out,
        unsigned short* __restrict__ zout, float* __restrict__ stats) {
    __shared__ float lwi[64], lbi[32], lwo[1024], lbo[32];
    __shared__ float zin[128][33];
    int t = threadIdx.x;
    int n = t >> 1, q = t & 1, c0 = q * 16;
    for (int i = t; i < 1024; i += 256) lwo[i] = w_out[i];
    if (t < 64) lwi[t] = w_in[t];
    if (t < 32) { lbi[t] = b_in[t]; lbo[t] = b_out[t]; }
    __syncthreads();
    int gid = blockIdx.x * 128 + n;
    bool act = gid < NN;
    int node = act ? perm[gid] : 0;
    float h0 = 0.f, h1 = 0.f;
    if (act) {
        int rs = rowptr[node], re = rowptr[node + 1];
        if (q == 0) {
            float2 self = *reinterpret_cast<const float2*>(x + 2 * (size_t)node);
            h0 = self.x; h1 = self.y;
        }
        float g0 = 0.f, g1 = 0.f;
        int k = rs + q;           // lane q takes every other neighbor
        for (; k + 6 < re; k += 8) {
            int s0 = csr[k], s1 = csr[k + 2], s2 = csr[k + 4], s3 = csr[k + 6];
            float2 v0 = *reinterpret_cast<const float2*>(x + 2 * (size_t)s0);
            float2 v1 = *reinterpret_cast<const float2*>(x + 2 * (size_t)s1);
            float2 v2 = *reinterpret_cast<const float2*>(x + 2 * (size_t)s2);
            float2 v3 = *reinterpret_cast<const float2*>(x + 2 * (size_t)s3);
            h0 += v0.x + v2.x; h1 += v0.y + v2.y;
            g0 += v1.x + v3.x; g1 += v1.y + v3.y;
        }
        for (; k < re; k += 2) {
            int s = csr[k];
            float2 v = *reinterpret_cast<const float2*>(x + 2 * (size_t)s);
            h0 += v.x; h1 += v.y;
        }
        h0 += g0; h1 += g1;
    }
    h0 += __shfl_xor(h0, 1);
    h1 += __shfl_xor(h1, 1);
    float y[16];
    #pragma unroll
    for (int j = 0; j < 16; j++) {
        float a = lbi[c0 + j] + h0 * lwi[c0 + j] + h1 * lwi[32 + c0 + j];
        y[j] = a > 0.f ? a : 0.f;
    }
    #pragma unroll
    for (int j = 0; j < 16; j++) zin[n][c0 + j] = act ? y[j] : 0.f;
    __syncthreads();
    float o[16];
    #pragma unroll
    for (int j = 0; j < 16; j++) o[j] = lbo[c0 + j];
    #pragma unroll
    for (int c = 0; c < 32; c++) {
        float yv = zin[n][c];
        #pragma unroll
        for (int j = 0; j < 16; j++) o[j] += yv * lwo[c * 32 + c0 + j];
    }
    #pragma unroll
    for (int j = 0; j < 16; j++) o[j] = o[j] > 0.f ? o[j] : 0.f;
    if (act) {
        unsigned short* zo = zout + (size_t)node * 32 + c0;
        uint4 wa, wb;
        wa.x = pack2(o[0], o[1]);   wa.y = pack2(o[2], o[3]);
        wa.z = pack2(o[4], o[5]);   wa.w = pack2(o[6], o[7]);
        wb.x = pack2(o[8], o[9]);   wb.y = pack2(o[10], o[11]);
        wb.z = pack2(o[12], o[13]); wb.w = pack2(o[14], o[15]);
        *reinterpret_cast<uint4*>(zo) = wa;
        *reinterpret_cast<uint4*>(zo + 8) = wb;
    }
    __syncthreads();
    #pragma unroll
    for (int j = 0; j < 16; j++) zin[n][c0 + j] = act ? o[j] : 0.f;
    __syncthreads();
    if (t < 32) {
        float s = 0.f, sq = 0.f;
        for (int nn = 0; nn < 128; nn++) {
            float v = zin[nn][t];
            s += v; sq += v * v;
        }
        atomicAdd(&stats[t], s);
        atomicAdd(&stats[32 + t], sq);
    }
}

// ======= heavy layer: 2 lanes/node, 128 nodes/block, 4-row unroll (r13) =====
__global__ __launch_bounds__(256) void gmlp32_k(
        const unsigned short* __restrict__ z, const int* __restrict__ perm,
        const float* __restrict__ statsIn,
        const float* __restrict__ gamma, const float* __restrict__ beta,
        const int* __restrict__ rowptr, const int* __restrict__ csr,
        const float* __restrict__ w_in, const float* __restrict__ b_in,
        const float* __restrict__ w_out, const float* __restrict__ b_out,
        unsigned short* __restrict__ zout, float* __restrict__ statsOut) {
    __shared__ float lwi[1024], lwo[1024], lbi[32], lbo[32], lsc[64];
    __shared__ float zin[128][33];
    int t = threadIdx.x;
    int n = t >> 1, q = t & 1, c0 = q * 16;
    for (int i = t; i < 1024; i += 256) { lwi[i] = w_in[i]; lwo[i] = w_out[i]; }
    if (t < 32) {
        lbi[t] = b_in[t]; lbo[t] = b_out[t];
        float mean = statsIn[t] * (1.f / NN);
        float var  = statsIn[32 + t] * (1.f / NN) - mean * mean;
        float scale = gamma[t] * rsqrtf(var + BN_EPS);
        lsc[t] = scale;
        lsc[32 + t] = beta[t] - mean * scale;
    }
    __syncthreads();
    int gid = blockIdx.x * 128 + n;
    bool act = gid < NN;
    int node = act ? perm[gid] : 0;
    float a[16];
    #pragma unroll
    for (int j = 0; j < 16; j++) a[j] = 0.f;
    float cntf = 0.f;
    if (act) {
        int rs = rowptr[node], re = rowptr[node + 1];
        cntf = (float)(re - rs + 1);
        const unsigned short* zb = z + (size_t)node * 32 + c0;
        uint4 sa = *reinterpret_cast<const uint4*>(zb);
        uint4 sb = *reinterpret_cast<const uint4*>(zb + 8);
        const unsigned short* pa = reinterpret_cast<const unsigned short*>(&sa);
        const unsigned short* pb = reinterpret_cast<const unsigned short*>(&sb);
        #pragma unroll
        for (int j = 0; j < 8; j++) { a[j] = h2f(pa[j]); a[8 + j] = h2f(pb[j]); }
        int k = rs;
        for (; k + 4 <= re; k += 4) {
            int s0 = csr[k], s1 = csr[k + 1], s2 = csr[k + 2], s3 = csr[k + 3];
            const unsigned short* r0 = z + (size_t)s0 * 32 + c0;
            const unsigned short* r1 = z + (size_t)s1 * 32 + c0;
            const unsigned short* r2 = z + (size_t)s2 * 32 + c0;
            const unsigned short* r3 = z + (size_t)s3 * 32 + c0;
            uint4 v0a = *reinterpret_cast<const uint4*>(r0);
            uint4 v0b = *reinterpret_cast<const uint4*>(r0 + 8);
            uint4 v1a = *reinterpret_cast<const uint4*>(r1);
            uint4 v1b = *reinterpret_cast<const uint4*>(r1 + 8);
            uint4 v2a = *reinterpret_cast<const uint4*>(r2);
            uint4 v2b = *reinterpret_cast<const uint4*>(r2 + 8);
            uint4 v3a = *reinterpret_cast<const uint4*>(r3);
            uint4 v3b = *reinterpret_cast<const uint4*>(r3 + 8);
            const unsigned short* q0a = reinterpret_cast<const unsigned short*>(&v0a);
            const unsigned short* q0b = reinterpret_cast<const unsigned short*>(&v0b);
            const unsigned short* q1a = reinterpret_cast<const unsigned short*>(&v1a);
            const unsigned short* q1b = reinterpret_cast<const unsigned short*>(&v1b);
            const unsigned short* q2a = reinterpret_cast<const unsigned short*>(&v2a);
            const unsigned short* q2b = reinterpret_cast<const unsigned short*>(&v2b);
            const unsigned short* q3a = reinterpret_cast<const unsigned short*>(&v3a);
            const unsigned short* q3b = reinterpret_cast<const unsigned short*>(&v3b);
            #pragma unroll
            for (int j = 0; j < 8; j++) {
                a[j]     += (h2f(q0a[j]) + h2f(q1a[j])) + (h2f(q2a[j]) + h2f(q3a[j]));
                a[8 + j] += (h2f(q0b[j]) + h2f(q1b[j])) + (h2f(q2b[j]) + h2f(q3b[j]));
            }
        }
        for (; k < re; k++) {
            int s = csr[k];
            const unsigned short* r = z + (size_t)s * 32 + c0;
            uint4 va = *reinterpret_cast<const uint4*>(r);
            uint4 vb = *reinterpret_cast<const uint4*>(r + 8);
            const unsigned short* qa = reinterpret_cast<const unsigned short*>(&va);
            const unsigned short* qb = reinterpret_cast<const unsigned short*>(&vb);
            #pragma unroll
            for (int j = 0; j < 8; j++) { a[j] += h2f(qa[j]); a[8 + j] += h2f(qb[j]); }
        }
    }
    #pragma unroll
    for (int j = 0; j < 16; j++)
        zin[n][c0 + j] = act ? (a[j] * lsc[c0 + j] + cntf * lsc[32 + c0 + j]) : 0.f;
    __syncthreads();
    float y[16];
    #pragma unroll
    for (int j = 0; j < 16; j++) y[j] = lbi[c0 + j];
    #pragma unroll
    for (int c = 0; c < 32; c++) {
        float zv = zin[n][c];
        #pragma unroll
        for (int j = 0; j < 16; j++) y[j] += zv * lwi[c * 32 + c0 + j];
    }
    #pragma unroll
    for (int j = 0; j < 16; j++) y[j] = y[j] > 0.f ? y[j] : 0.f;
    __syncthreads();
    #pragma unroll
    for (int j = 0; j < 16; j++) zin[n][c0 + j] = y[j];
    __syncthreads();
    float o[16];
    #pragma unroll
    for (int j = 0; j < 16; j++) o[j] = lbo[c0 + j];
    #pragma unroll
    for (int c = 0; c < 32; c++) {
        float yv = zin[n][c];
        #pragma unroll
        for (int j = 0; j < 16; j++) o[j] += yv * lwo[c * 32 + c0 + j];
    }
    #pragma unroll
    for (int j = 0; j < 16; j++) o[j] = o[j] > 0.f ? o[j] : 0.f;
    if (act) {
        unsigned short* zo = zout + (size_t)node * 32 + c0;
        uint4 wa, wb;
        wa.x = pack2(o[0], o[1]);   wa.y = pack2(o[2], o[3]);
        wa.z = pack2(o[4], o[5]);   wa.w = pack2(o[6], o[7]);
        wb.x = pack2(o[8], o[9]);   wb.y = pack2(o[10], o[11]);
        wb.z = pack2(o[12], o[13]); wb.w = pack2(o[14], o[15]);
        *reinterpret_cast<uint4*>(zo) = wa;
        *reinterpret_cast<uint4*>(zo + 8) = wb;
    }
    __syncthreads();
    #pragma unroll
    for (int j = 0; j < 16; j++) zin[n][c0 + j] = act ? o[j] : 0.f;
    __syncthreads();
    if (t < 32) {
        float s = 0.f, sq = 0.f;
        for (int nn = 0; nn < 128; nn++) {
            float v = zin[nn][t];
            s += v; sq += v * v;
        }
        atomicAdd(&statsOut[t], s);
        atomicAdd(&statsOut[32 + t], sq);
    }
}

// ====== pool: batch is SORTED -> one block per graph, binary search ======
__global__ __launch_bounds__(256) void pool_seg_k(
        const unsigned short* __restrict__ z,
        const float* __restrict__ statsIn,
        const float* __restrict__ gamma, const float* __restrict__ beta,
        const int* __restrict__ batch, float* __restrict__ g) {
    __shared__ float lsc[64];
    __shared__ float part[32][33];
    int t = threadIdx.x, slot = t >> 3, q = t & 7, c0 = q * 4;
    int gr = blockIdx.x;
    if (t < 32) {
        float mean = statsIn[t] * (1.f / NN);
        float var  = statsIn[32 + t] * (1.f / NN) - mean * mean;
        float scale = gamma[t] * rsqrtf(var + BN_EPS);
        lsc[t] = scale;
        lsc[32 + t] = beta[t] - mean * scale;
    }
    int lo = 0, hi = NN;
    while (lo < hi) { int mid = (lo + hi) >> 1; if (batch[mid] < gr) lo = mid + 1; else hi = mid; }
    int start = lo;
    hi = NN;
    while (lo < hi) { int mid = (lo + hi) >> 1; if (batch[mid] < gr + 1) lo = mid + 1; else hi = mid; }
    int end = lo;
    float a0 = 0.f, a1 = 0.f, a2 = 0.f, a3 = 0.f;
    for (int i = start + slot; i < end; i += 32) {
        ushort4 v = *reinterpret_cast<const ushort4*>(z + (size_t)i * 32 + c0);
        a0 += h2f(v.x); a1 += h2f(v.y); a2 += h2f(v.z); a3 += h2f(v.w);
    }
    part[slot][c0+0] = a0; part[slot][c0+1] = a1;
    part[slot][c0+2] = a2; part[slot][c0+3] = a3;
    __syncthreads();
    if (t < 32) {
        float s = 0.f;
        for (int sl = 0; sl < 32; sl++) s += part[sl][t];
        float cnt = (float)(end - start);
        g[(size_t)gr * 32 + t] = s * lsc[t] + cnt * lsc[32 + t];
    }
}

// ---------------- head: fc1 -> relu -> fc2 -> log_softmax ----------------
__global__ __launch_bounds__(256) void head_k(
        const float* __restrict__ g,
        const float* __restrict__ fc1w, const float* __restrict__ fc1b,
        const float* __restrict__ fc2w, const float* __restrict__ fc2b,
        float* __restrict__ out) {
    __shared__ float lw1[1024], lb1[32], lw2[64], lb2[2];
    int t = threadIdx.x;
    for (int i = t; i < 1024; i += 256) lw1[i] = fc1w[i];
    if (t < 32) lb1[t] = fc1b[t];
    if (t < 64) lw2[t] = fc2w[t];
    if (t < 2) lb2[t] = fc2b[t];
    __syncthreads();
    float gv[32];
    #pragma unroll
    for (int c = 0; c < 32; c++) gv[c] = g[(size_t)t * 32 + c];
    float o0 = lb2[0], o1 = lb2[1];
    #pragma unroll 4
    for (int k = 0; k < 32; k++) {
        float a = lb1[k];
        #pragma unroll
        for (int c = 0; c < 32; c++) a += gv[c] * lw1[c * 32 + k];
        a = a > 0.f ? a : 0.f;
        o0 += a * lw2[k * 2 + 0];
        o1 += a * lw2[k * 2 + 1];
    }
    float m = fmaxf(o0, o1);
    float lse = m + logf(expf(o0 - m) + expf(o1 - m));
    out[t * 2 + 0] = o0 - lse;
    out[t * 2 + 1] = o1 - lse;
}

extern "C" void kernel_launch(void* const* d_in, const int* in_sizes, int n_in,
                              void* d_out, int out_size, void* d_ws, size_t ws_size,
                              hipStream_t stream) {
    const float* x      = (const float*)d_in[0];
    const int*   ei     = (const int*)d_in[1];
    const int*   src    = ei;
    const int*   dst    = ei + NE;
    const int*   batch  = (const int*)d_in[2];
    const float* w1_in  = (const float*)d_in[3];
    const float* b1_in  = (const float*)d_in[4];
    const float* w1_out = (const float*)d_in[5];
    const float* b1_out = (const float*)d_in[6];
    const float* ws_in  = (const float*)d_in[7];
    const float* bs_in  = (const float*)d_in[8];
    const float* ws_out = (const float*)d_in[9];
    const float* bs_out = (const float*)d_in[10];
    const float* gamma  = (const float*)d_in[11];
    const float* beta   = (const float*)d_in[12];
    const float* fc1w   = (const float*)d_in[13];
    const float* fc1b   = (const float*)d_in[14];
    const float* fc2w   = (const float*)d_in[15];
    const float* fc2b   = (const float*)d_in[16];
    float* out = (float*)d_out;

    // ---- workspace layout (16B alignment maintained) ----
    unsigned short* bufA = (unsigned short*)d_ws;        // NN*32 fp16
    unsigned short* bufB = bufA + (size_t)NN * 32;       // NN*32 fp16
    float* stats  = (float*)(bufB + (size_t)NN * 32);    // 5*64 (zeroed)
    int*   bcur   = (int*)(stats + 5 * 64);              // NPART (zeroed, adjacent)
    float* g      = (float*)(bcur + NPART);              // NG*32
    int*   perm   = (int*)(g + (size_t)NG * 32);         // NN
    int*   rowptr = perm + NN;                           // NN+4
    int*   csr    = rowptr + NN + 4;                     // NE
    unsigned int* bpk = (unsigned int*)(csr + NE);       // NPART*CAP

    // ---- zero stats + bucket cursors in one memset ----
    hipMemsetAsync(stats, 0, (size_t)(5 * 64 + NPART) * sizeof(int), stream);

    // ---- CSR build ----
    bucket_k<<<NBLK, 256, 0, stream>>>(src, dst, bcur, bpk);
    build_k<<<NPART, 256, 0, stream>>>(bcur, bpk, rowptr, csr, perm);

    // ---- layer 1 (input dim 2) -> stats[0] ----
    gmlp1_k<<<(NN + 127) / 128, 256, 0, stream>>>(x, perm, rowptr, csr,
                                                  w1_in, b1_in, w1_out, b1_out, bufA, stats);

    // ---- layers 2..5 (input dim 32); BN(j) recomputed in-block ----
    const unsigned short* cur = bufA;
    unsigned short* nxt = bufB;
    for (int j = 0; j < 4; j++) {
        gmlp32_k<<<(NN + 127) / 128, 256, 0, stream>>>(cur, perm, stats + j * 64,
                                              gamma + j * 32, beta + j * 32,
                                              rowptr, csr,
                                              ws_in + j * 1024, bs_in + j * 32,
                                              ws_out + j * 1024, bs_out + j * 32,
                                              nxt, stats + (j + 1) * 64);
        unsigned short* tmp = (unsigned short*)cur; cur = nxt; nxt = tmp;
    }

    // ---- pool (BN(4) in-block) + head ----
    pool_seg_k<<<NG, 256, 0, stream>>>(cur, stats + 4 * 64,
                                       gamma + 4 * 32, beta + 4 * 32, batch, g);
    head_k<<<1, 256, 0, stream>>>(g, fc1w, fc1b, fc2w, fc2b, out);
}